// Round 13
// baseline (384.820 us; speedup 1.0000x reference)
//
#include <hip/hip_runtime.h>
#include <hip/hip_bf16.h>
#include <math.h>

#define NN 100000
#define NE 1600000
#define NG 128
#define H 128
#define DMAX 64   // padded CSR slots/node; P(deg>64 | Poisson16) ~ 1e-17
#define NB 391    // dst-buckets of 256 nodes
#define BCAP 5120 // bucket edge capacity (mean 4092, +16 sigma)
#define NBK 1024  // bucket-build blocks (R25: was 512; 2 blocks/CU -> 4)
#define EPB 1563  // edges per bucket-build block (1024 x 1563 >= NE, tail-guarded)

typedef __attribute__((ext_vector_type(8))) short short8;
typedef __attribute__((ext_vector_type(4))) float floatx4;
typedef __attribute__((ext_vector_type(2))) float floatx2;
typedef __attribute__((ext_vector_type(4))) int intx4;       // nt-builtin-safe
typedef __attribute__((ext_vector_type(4))) unsigned uintx4; // nt-builtin-safe
typedef __attribute__((ext_vector_type(2))) unsigned uintx2; // nt-builtin-safe

// R21 (do not re-try): fp8 row parity-plane split keyed to bid%8 REGRESSED
// (FETCH 95->135 MB): parity->XCD separation doesn't hold, packed half-rows
// share L2 lines, colp/fcnt reads double. Contiguous 128B row = one L2 line
// per gathered neighbor; FETCH == compulsory model.
// R23 (do not re-try): 16B/lane gather (8 lanes/row, 3125 blocks) NULLED —
// halved instructions but halved wave count (occ 57->30%), dur unchanged.
// The gather is fabric-SERVICE-bound, not issue-bound. Gather load side is
// closed: 8B/lane, 6250 blocks, FETCH at compulsory floor.
// R24 (do not re-try): fp8 agg buffer FAILED correctness (absmax 0.484 >>
// threshold 0.02). agg = POST-SUM values up to ~50; e4m3 step there is 2-4
// ABSOLUTE. Quantize-before-sum ok (errors average over ~16 nbrs);
// quantize-after-sum is not. agg stays bf16.
// R22: bf16 ping-pong activation buffers eliminated (GEMMs read X from fp8;
// e4m3->bf16 exact). absmax bit-identical 0.0039 (threshold 0.02).
// R25 (this round): (a) MFMA GEMMs prefetch ALL 24 operand loads to regs
// before the staging barrier — at 64KB-LDS occupancy (2 waves/SIMD) the
// per-kt load->MFMA chain exposed ~500cy latency 8x/wave; (b) k_bucket
// 512->1024 blocks (was 2 blocks/CU, half the GPU idle); (c) k_agg4b+k_gemm4
// fused into k_l1 (kills agg4 roundtrip + a launch).

// ---------------- init (gbase/gsum/f8 sentinel rows) + W conversion --------
// R18 layout: wf[t], t = kt*4096 + ct*512 + lane*8 + j  holds the fragment
// element W'[kt*32 + (lane>>4)*8 + j][ct*16 + (lane&15)] — fragments in exact
// read order; also makes the R19 LDS stage a straight linear 64 KB copy.
__global__ void k_init_wcvt(int* __restrict__ gbase, float* __restrict__ gsum,
                            unsigned* __restrict__ rowF8a, unsigned* __restrict__ rowF8b,
                            const float* __restrict__ Wr1, const float* __restrict__ Wo1,
                            const float* __restrict__ Wr2, const float* __restrict__ Wo2,
                            const float* __restrict__ Wr3, const float* __restrict__ Wo3,
                            __hip_bfloat16* __restrict__ wf) {
  if (blockIdx.x < 384) {  // W conversion: 3*32768 elements
    int t = blockIdx.x * 256 + threadIdx.x;
    int L = t >> 15, tt = t & 32767;
    const float* Wr = (L == 0) ? Wr1 : (L == 1) ? Wr2 : Wr3;
    const float* Wo = (L == 0) ? Wo1 : (L == 1) ? Wo2 : Wo3;
    int j = tt & 7, lanex = (tt >> 3) & 63, ct = (tt >> 9) & 7, kt = tt >> 12;
    int lr = lanex & 15, quad = lanex >> 4;
    int n = ct * 16 + lr;
    int r = kt * 32 + quad * 8 + j;
    float v = (r < 128) ? Wr[r * 128 + n] : Wo[(r - 128) * 128 + n];
    wf[t] = __float2bfloat16(v);
  } else {  // init
    int t = (blockIdx.x - 384) * 256 + threadIdx.x;
    if (t < NB) gbase[t] = 0;
    else if (t < NB + NG * H) gsum[t - NB] = 0.f;
    else if (t < NB + NG * H + 32) rowF8a[t - NB - NG * H] = 0u;
    else if (t < NB + NG * H + 64) rowF8b[t - NB - NG * H - 32] = 0u;
  }
}

// ---------------- two-phase CSR build ----------------
// R14: LDS counting-sort so pair-appends are coalesced bursts instead of 8 B
// random scatter. One global atomicAdd per (block,bucket).
// R25: 1024 blocks (4/CU occupancy; LDS ~21 KB/block), tail-guarded.
__global__ __launch_bounds__(256) void k_bucket(const int* __restrict__ ei,
                                                int* __restrict__ gbase,
                                                int2* __restrict__ pairs) {
  __shared__ int scnt[512];   // histogram, padded for scan; reused as fill ctr
  __shared__ int soff[NB];    // local exclusive offsets
  __shared__ int sbase[NB];   // global reserved base
  __shared__ int2 stg[EPB];   // bucket-sorted staging (12.5 KB)
  __shared__ short sbkt[EPB]; // bucket id per staged edge
  const int tid = threadIdx.x;
  const int e0 = blockIdx.x * EPB;
  int eend = e0 + EPB; if (eend > NE) eend = NE;
  const int nloc = eend - e0;
  const int* dst = ei + NE;

  scnt[tid] = 0;
  scnt[tid + 256] = 0;
  __syncthreads();
  for (int e = e0 + tid; e < eend; e += 256) {
    int d = __builtin_nontemporal_load(dst + e);
    atomicAdd(&scnt[d >> 8], 1);
  }
  __syncthreads();
  int c0 = scnt[tid], c1 = scnt[tid + 256];
  // inclusive Hillis-Steele scan over 512 entries (256 threads x 2)
  for (int off = 1; off < 512; off <<= 1) {
    int v0 = (tid >= off) ? scnt[tid - off] : 0;
    int v1 = (tid + 256 >= off) ? scnt[tid + 256 - off] : 0;
    __syncthreads();
    scnt[tid] += v0;
    scnt[tid + 256] += v1;
    __syncthreads();
  }
  if (tid < NB) {
    soff[tid] = scnt[tid] - c0;
    sbase[tid] = c0 ? atomicAdd(&gbase[tid], c0) : 0;
  }
  if (tid + 256 < NB) {
    soff[tid + 256] = scnt[tid + 256] - c1;
    sbase[tid + 256] = c1 ? atomicAdd(&gbase[tid + 256], c1) : 0;
  }
  __syncthreads();
  scnt[tid] = 0;
  scnt[tid + 256] = 0;
  __syncthreads();
  for (int e = e0 + tid; e < eend; e += 256) {
    int d = __builtin_nontemporal_load(dst + e);
    int s = __builtin_nontemporal_load(ei + e);
    int b = d >> 8;
    int p = soff[b] + atomicAdd(&scnt[b], 1);
    stg[p] = make_int2(s, d);
    sbkt[p] = (short)b;
  }
  __syncthreads();
  for (int i = tid; i < nloc; i += 256) {
    int b = sbkt[i];
    int gpos = sbase[b] + (i - soff[b]);
    if (gpos < BCAP) pairs[(size_t)b * BCAP + gpos] = stg[i];  // coalesced runs
  }
}

// Phase 2: one block OWNS one 256-dst bucket -> counters in LDS (no global
// atomics), colp slice single-writer, fcnt written directly.
__global__ __launch_bounds__(256) void k_fill2(const int2* __restrict__ pairs,
                                               const int* __restrict__ gbase,
                                               int* __restrict__ fcnt,
                                               int* __restrict__ colp) {
  __shared__ int scnt[256];
  const int b = blockIdx.x;
  const int d0 = b << 8;
  const int tid = threadIdx.x;
  scnt[tid] = 0;
  __syncthreads();
  int n = gbase[b];
  if (n > BCAP) n = BCAP;
  const int2* pp = pairs + (size_t)b * BCAP;
  for (int e = tid; e < n; e += 256) {
    int2 sd = pp[e];  // coalesced
    int dl = sd.y - d0;
    int pos = atomicAdd(&scnt[dl], 1);  // LDS int atomic (native, fast)
    if (pos < DMAX) colp[((size_t)(d0 + dl) << 6) + pos] = sd.x;
  }
  __syncthreads();
  int d = d0 + tid;
  if (d < NN) {
    int c = scnt[tid];
    fcnt[d] = (c > DMAX) ? DMAX : c;
  }
}

// ---------------- bf16/fp8 helpers ----------------
__device__ inline unsigned pk_bf16(float a, float b) {  // RNE pack (lo=a, hi=b)
  unsigned ua = __float_as_uint(a), ub = __float_as_uint(b);
  ua = (ua + 0x7fffu + ((ua >> 16) & 1u)) >> 16;
  ub = (ub + 0x7fffu + ((ub >> 16) & 1u)) & 0xffff0000u;
  return ua | ub;
}

// 8 packed OCP e4m3 (one uint2) dequant + accumulate into fp32[8].
// gfx950 hardware cvt: v_cvt_pk_f32_fp8 (bytes {0,1} sel=0, {2,3} sel=1).
__device__ inline void accf8(float* a, uint2 u) {
  floatx2 p;
  p = __builtin_amdgcn_cvt_pk_f32_fp8((int)u.x, false); a[0] += p.x; a[1] += p.y;
  p = __builtin_amdgcn_cvt_pk_f32_fp8((int)u.x, true);  a[2] += p.x; a[3] += p.y;
  p = __builtin_amdgcn_cvt_pk_f32_fp8((int)u.y, false); a[4] += p.x; a[5] += p.y;
  p = __builtin_amdgcn_cvt_pk_f32_fp8((int)u.y, true);  a[6] += p.x; a[7] += p.y;
}

// 8 packed e4m3 -> 8 bf16 (EXACT: e4m3 values are exactly representable in
// bf16, so f32->bf16 truncation loses nothing).
__device__ inline short8 f8x8_bf16(uintx2 u) {
  floatx2 p0 = __builtin_amdgcn_cvt_pk_f32_fp8((int)u.x, false);
  floatx2 p1 = __builtin_amdgcn_cvt_pk_f32_fp8((int)u.x, true);
  floatx2 p2 = __builtin_amdgcn_cvt_pk_f32_fp8((int)u.y, false);
  floatx2 p3 = __builtin_amdgcn_cvt_pk_f32_fp8((int)u.y, true);
  union { uintx4 u; short8 s; } cv;
  cv.u.x = (__float_as_uint(p0.y) & 0xffff0000u) | (__float_as_uint(p0.x) >> 16);
  cv.u.y = (__float_as_uint(p1.y) & 0xffff0000u) | (__float_as_uint(p1.x) >> 16);
  cv.u.z = (__float_as_uint(p2.y) & 0xffff0000u) | (__float_as_uint(p2.x) >> 16);
  cv.u.w = (__float_as_uint(p3.y) & 0xffff0000u) | (__float_as_uint(p3.x) >> 16);
  return cv.s;
}

// ---------------- aggregation (fp8 gather payload, fp32 acc, bf16 agg) ----
// R17: fp8 e4m3 payload halves the compulsory gather row to 128 B (= exactly
// one L2 line per neighbor). FETCH 95 MB == compulsory model (88.2 gather +
// 6.4 colp + 0.4 fcnt): zero capacity misses, ~86% of fabric line rate.
// At structural floor — do not touch (see R21/R23/R24 notes).
__global__ void k_aggf8(const uint2* __restrict__ xf8, const int* __restrict__ fcnt,
                        const int* __restrict__ colp, uintx4* __restrict__ agg) {
  int w = (blockIdx.x * blockDim.x + threadIdx.x) >> 6;
  int lane = threadIdx.x & 63;
  int qr = lane >> 4, ql = lane & 15;  // qr: node-of-wave, ql: 8B chunk of row
  int node = 4 * w + qr;
  if (node >= NN) return;
  int cnt = fcnt[node];
  cnt = (cnt + 3) & ~3;
  const int* cp = colp + (node << 6);
  float a0[8] = {0}, a1[8] = {0}, a2[8] = {0}, a3[8] = {0};
  for (int i = 0; i < cnt; i += 4) {
    intx4 ss = __builtin_nontemporal_load((const intx4*)(cp + i));
    uint2 u0 = xf8[(size_t)ss.x * 16 + ql];
    uint2 u1 = xf8[(size_t)ss.y * 16 + ql];
    uint2 u2 = xf8[(size_t)ss.z * 16 + ql];
    uint2 u3 = xf8[(size_t)ss.w * 16 + ql];
    accf8(a0, u0);
    accf8(a1, u1);
    accf8(a2, u2);
    accf8(a3, u3);
  }
  float s[8];
#pragma unroll
  for (int t = 0; t < 8; ++t) s[t] = (a0[t] + a1[t]) + (a2[t] + a3[t]);
  uintx4 o;
  o.x = pk_bf16(s[0], s[1]);
  o.y = pk_bf16(s[2], s[3]);
  o.z = pk_bf16(s[4], s[5]);
  o.w = pk_bf16(s[6], s[7]);
  __builtin_nontemporal_store(o, agg + (size_t)node * 16 + ql);
}

// ---------------- layer 1 fused: agg(F_IN=4) + GEMM(K=4+4) -> fp8 ----------
// R25: k_agg4b + k_gemm4 fused. 16 threads/node: gather neighbors in x-space
// (stride-16), 16-lane butterfly leaves the full agg4 row in every lane,
// then each thread computes 8 output cols. Also writes the <=3 colp sentinel
// slots per node (NN = zeroed row) needed by k_aggf8.
__global__ __launch_bounds__(256) void k_l1(
    const float* __restrict__ x, const int* __restrict__ fcnt,
    int* __restrict__ colp,
    const float* __restrict__ Wr, const float* __restrict__ Wo,
    const float* __restrict__ br, unsigned char* __restrict__ out8) {
  __shared__ float sWr[512], sWo[512], sbr[128];
  const int tid = threadIdx.x;
  sWr[tid] = Wr[tid]; sWr[tid + 256] = Wr[tid + 256];
  sWo[tid] = Wo[tid]; sWo[tid + 256] = Wo[tid + 256];
  if (tid < 128) sbr[tid] = br[tid];

  const int node = blockIdx.x * 16 + (tid >> 4);  // 6250*16 = NN exactly
  const int q = tid & 15;
  const int cnt = fcnt[node];
  // sentinel padding for k_aggf8 (round cnt up to multiple of 4)
  if (q < 4) {
    int up = (cnt + 3) & ~3;
    int pi = cnt + q;
    if (pi < up) colp[(node << 6) + pi] = NN;
  }
  const int* cp = colp + (node << 6);
  float4 acc = make_float4(0.f, 0.f, 0.f, 0.f);
  for (int e = q; e < cnt; e += 16) {
    float4 v = ((const float4*)x)[cp[e]];  // lanes q=0..15 read cp[e..e+15]: coalesced
    acc.x += v.x; acc.y += v.y; acc.z += v.z; acc.w += v.w;
  }
#pragma unroll
  for (int d = 1; d < 16; d <<= 1) {  // 16-lane butterfly: all lanes get the sum
    acc.x += __shfl_xor(acc.x, d);
    acc.y += __shfl_xor(acc.y, d);
    acc.z += __shfl_xor(acc.z, d);
    acc.w += __shfl_xor(acc.w, d);
  }
  float4 xv = ((const float4*)x)[node];  // broadcast across the 16 lanes
  __syncthreads();  // weight staging visible

  const int j0 = q * 8;
  float4 b0 = *(const float4*)&sbr[j0];
  float4 b1 = *(const float4*)&sbr[j0 + 4];
  float v[8] = {b0.x, b0.y, b0.z, b0.w, b1.x, b1.y, b1.z, b1.w};
#pragma unroll
  for (int k = 0; k < 4; ++k) {
    float ak = (k == 0) ? acc.x : (k == 1) ? acc.y : (k == 2) ? acc.z : acc.w;
    float xk = (k == 0) ? xv.x : (k == 1) ? xv.y : (k == 2) ? xv.z : xv.w;
    float4 wr0 = *(const float4*)&sWr[k * 128 + j0];
    float4 wr1 = *(const float4*)&sWr[k * 128 + j0 + 4];
    float4 wo0 = *(const float4*)&sWo[k * 128 + j0];
    float4 wo1 = *(const float4*)&sWo[k * 128 + j0 + 4];
    v[0] = fmaf(ak, wr0.x, fmaf(xk, wo0.x, v[0]));
    v[1] = fmaf(ak, wr0.y, fmaf(xk, wo0.y, v[1]));
    v[2] = fmaf(ak, wr0.z, fmaf(xk, wo0.z, v[2]));
    v[3] = fmaf(ak, wr0.w, fmaf(xk, wo0.w, v[3]));
    v[4] = fmaf(ak, wr1.x, fmaf(xk, wo1.x, v[4]));
    v[5] = fmaf(ak, wr1.y, fmaf(xk, wo1.y, v[5]));
    v[6] = fmaf(ak, wr1.z, fmaf(xk, wo1.z, v[6]));
    v[7] = fmaf(ak, wr1.w, fmaf(xk, wo1.w, v[7]));
  }
#pragma unroll
  for (int jj = 0; jj < 8; ++jj) v[jj] = fmaxf(v[jj], 0.f);
  unsigned w8a, w8b;
  w8a = (unsigned)__builtin_amdgcn_cvt_pk_fp8_f32(v[0], v[1], 0, false);
  w8a = (unsigned)__builtin_amdgcn_cvt_pk_fp8_f32(v[2], v[3], (int)w8a, true);
  w8b = (unsigned)__builtin_amdgcn_cvt_pk_fp8_f32(v[4], v[5], 0, false);
  w8b = (unsigned)__builtin_amdgcn_cvt_pk_fp8_f32(v[6], v[7], (int)w8b, true);
  uint2 o8; o8.x = w8a; o8.y = w8b;
  *(uint2*)(out8 + (size_t)node * H + j0) = o8;
}

// ---------------- MFMA GEMM: relu([agg|x] @ [Wr;Wo] + br) -> fp8 -----------
// R18: operand-swapped MFMA + packed stores. R19: weights staged once per
// block into LDS. R22: X read from fp8 (exact cvt to bf16 fragments).
// R25: ALL 24 operand loads issued before the staging barrier — at 64KB-LDS
// occupancy (2 waves/SIMD) the old per-kt load->MFMA chain exposed ~500cy
// latency 8x per wave; now 24-deep memory parallelism overlapping staging.
__global__ __launch_bounds__(256) void k_gemm_mfma(
    const __hip_bfloat16* __restrict__ A, const unsigned char* __restrict__ X8,
    const __hip_bfloat16* __restrict__ Wf, const float* __restrict__ br,
    unsigned char* __restrict__ out8) {
  __shared__ short8 sw[4096];  // 64 KB: full [Wr;Wo] fragment tile
  const int tid = threadIdx.x;
  const int wv = tid >> 6, lane = tid & 63;
  const int quad = lane >> 4, lr = lane & 15;
  const int mbase = blockIdx.x * 128 + wv * 32;

  int r0 = mbase + lr;      if (r0 > NN - 1) r0 = NN - 1;
  int r1 = mbase + 16 + lr; if (r1 > NN - 1) r1 = NN - 1;

  // prefetch all operands (R25)
  short8 a0r[4], a1r[4];
  uintx2 x0r[4], x1r[4];
#pragma unroll
  for (int k = 0; k < 4; ++k) {
    const size_t koff = (size_t)k * 32 + quad * 8;
    a0r[k] = __builtin_nontemporal_load((const short8*)(A + (size_t)r0 * H + koff));
    a1r[k] = __builtin_nontemporal_load((const short8*)(A + (size_t)r1 * H + koff));
  }
#pragma unroll
  for (int k = 0; k < 4; ++k) {
    const size_t koff = (size_t)k * 32 + quad * 8;
    x0r[k] = __builtin_nontemporal_load((const uintx2*)(X8 + (size_t)r0 * H + koff));
    x1r[k] = __builtin_nontemporal_load((const uintx2*)(X8 + (size_t)r1 * H + koff));
  }

#pragma unroll
  for (int i = 0; i < 16; ++i)  // linear 64 KB copy (wf already in read order)
    sw[i * 256 + tid] = ((const short8*)Wf)[i * 256 + tid];

  floatx4 acc[2][8];
#pragma unroll
  for (int rt = 0; rt < 2; ++rt)
#pragma unroll
    for (int ct = 0; ct < 8; ++ct) acc[rt][ct] = (floatx4){0.f, 0.f, 0.f, 0.f};

  __syncthreads();

#pragma unroll
  for (int kt = 0; kt < 8; ++kt) {
    short8 a0 = (kt < 4) ? a0r[kt] : f8x8_bf16(x0r[kt - 4]);
    short8 a1 = (kt < 4) ? a1r[kt] : f8x8_bf16(x1r[kt - 4]);
#pragma unroll
    for (int ct = 0; ct < 8; ++ct) {
      short8 b = sw[kt * 512 + ct * 64 + lane];  // conflict-free ds_read_b128
      // swapped operands: lane lr owns row mbase+rt*16+lr, cols ct*16+quad*4+rg
      acc[0][ct] = __builtin_amdgcn_mfma_f32_16x16x32_bf16(b, a0, acc[0][ct], 0, 0, 0);
      acc[1][ct] = __builtin_amdgcn_mfma_f32_16x16x32_bf16(b, a1, acc[1][ct], 0, 0, 0);
    }
  }

  floatx4 bias4[8];
#pragma unroll
  for (int ct = 0; ct < 8; ++ct)
    bias4[ct] = *(const floatx4*)(br + ct * 16 + quad * 4);

#pragma unroll
  for (int rt = 0; rt < 2; ++rt) {
    int row = mbase + rt * 16 + lr;
    if (row < NN) {
#pragma unroll
      for (int ct = 0; ct < 8; ++ct) {
        float v0 = fmaxf(acc[rt][ct][0] + bias4[ct].x, 0.f);
        float v1 = fmaxf(acc[rt][ct][1] + bias4[ct].y, 0.f);
        float v2 = fmaxf(acc[rt][ct][2] + bias4[ct].z, 0.f);
        float v3 = fmaxf(acc[rt][ct][3] + bias4[ct].w, 0.f);
        unsigned w8 = 0;
        w8 = (unsigned)__builtin_amdgcn_cvt_pk_fp8_f32(v0, v1, (int)w8, false);
        w8 = (unsigned)__builtin_amdgcn_cvt_pk_fp8_f32(v2, v3, (int)w8, true);
        *(unsigned*)(out8 + (size_t)row * H + ct * 16 + quad * 4) = w8;
      }
    }
  }
}

// ---------------- layer-4 MFMA GEMM fused with global mean-pool ------------
// R15: never store x4; pool it in the GEMM epilogue.
// R16: atomic-free epilogue (LDS float atomicAdd lowers to CAS retry loops).
// R19: LDS weight staging. R22: X read from fp8. R25: operand prefetch.
// Keeps the ORIGINAL operand order (column-per-lane C/D): the pool epilogue
// reduces along rows with a fixed column per lane; no global stores to pack.
__global__ __launch_bounds__(256) void k_gemm_mfma_pool(
    const __hip_bfloat16* __restrict__ A, const unsigned char* __restrict__ X8,
    const __hip_bfloat16* __restrict__ Wf, const float* __restrict__ br,
    const int* __restrict__ batch, float* __restrict__ gsum) {
  __shared__ short8 sw[4096];      // 64 KB weight tile
  __shared__ float pool[4][2][H];  // [wave][segment][column], 4 KB
  const int tid = threadIdx.x;
  const int wv = tid >> 6, lane = tid & 63;
  const int quad = lane >> 4, lr = lane & 15;
  const int bbase = blockIdx.x * 128;
  const int mbase = bbase + wv * 32;

  int r0 = mbase + lr;      if (r0 > NN - 1) r0 = NN - 1;
  int r1 = mbase + 16 + lr; if (r1 > NN - 1) r1 = NN - 1;

  short8 a0r[4], a1r[4];
  uintx2 x0r[4], x1r[4];
#pragma unroll
  for (int k = 0; k < 4; ++k) {
    const size_t koff = (size_t)k * 32 + quad * 8;
    a0r[k] = __builtin_nontemporal_load((const short8*)(A + (size_t)r0 * H + koff));
    a1r[k] = __builtin_nontemporal_load((const short8*)(A + (size_t)r1 * H + koff));
  }
#pragma unroll
  for (int k = 0; k < 4; ++k) {
    const size_t koff = (size_t)k * 32 + quad * 8;
    x0r[k] = __builtin_nontemporal_load((const uintx2*)(X8 + (size_t)r0 * H + koff));
    x1r[k] = __builtin_nontemporal_load((const uintx2*)(X8 + (size_t)r1 * H + koff));
  }

#pragma unroll
  for (int i = 0; i < 16; ++i)
    sw[i * 256 + tid] = ((const short8*)Wf)[i * 256 + tid];

  floatx4 acc[2][8];
#pragma unroll
  for (int rt = 0; rt < 2; ++rt)
#pragma unroll
    for (int ct = 0; ct < 8; ++ct) acc[rt][ct] = (floatx4){0.f, 0.f, 0.f, 0.f};

  __syncthreads();

#pragma unroll
  for (int kt = 0; kt < 8; ++kt) {
    short8 a0 = (kt < 4) ? a0r[kt] : f8x8_bf16(x0r[kt - 4]);
    short8 a1 = (kt < 4) ? a1r[kt] : f8x8_bf16(x1r[kt - 4]);
#pragma unroll
    for (int ct = 0; ct < 8; ++ct) {
      short8 b = sw[kt * 512 + ct * 64 + lane];
      acc[0][ct] = __builtin_amdgcn_mfma_f32_16x16x32_bf16(a0, b, acc[0][ct], 0, 0, 0);
      acc[1][ct] = __builtin_amdgcn_mfma_f32_16x16x32_bf16(a1, b, acc[1][ct], 0, 0, 0);
    }
  }

  const int g0 = batch[bbase];  // block-uniform (bbase <= 99968 < NN)
  float bias[8];
#pragma unroll
  for (int ct = 0; ct < 8; ++ct) bias[ct] = br[ct * 16 + lr];

  // Per-thread segment-split sums over this thread's 8 rows. Static indices
  // only (ps0/ps1 named arrays) so they stay in VGPRs (rule #20).
  float ps0[8] = {0.f, 0.f, 0.f, 0.f, 0.f, 0.f, 0.f, 0.f};
  float ps1[8] = {0.f, 0.f, 0.f, 0.f, 0.f, 0.f, 0.f, 0.f};
#pragma unroll
  for (int rt = 0; rt < 2; ++rt) {
#pragma unroll
    for (int rg = 0; rg < 4; ++rg) {
      int row = mbase + rt * 16 + quad * 4 + rg;
      if (row < NN) {
        if (batch[row] == g0) {
#pragma unroll
          for (int ct = 0; ct < 8; ++ct)
            ps0[ct] += fmaxf(acc[rt][ct][rg] + bias[ct], 0.f);
        } else {
#pragma unroll
          for (int ct = 0; ct < 8; ++ct)
            ps1[ct] += fmaxf(acc[rt][ct][rg] + bias[ct], 0.f);
        }
      }
    }
  }

  // Fold the 4 quads (lanes lr, lr+16, lr+32, lr+48 share column ct*16+lr).
#pragma unroll
  for (int ct = 0; ct < 8; ++ct) {
    float a = ps0[ct];
    a += __shfl_xor(a, 16);
    a += __shfl_xor(a, 32);
    float b = ps1[ct];
    b += __shfl_xor(b, 16);
    b += __shfl_xor(b, 32);
    if (quad == 0) {  // 16 lanes x 8 ct -> full 128-column wave partials
      pool[wv][0][ct * 16 + lr] = a;
      pool[wv][1][ct * 16 + lr] = b;
    }
  }
  __syncthreads();

  if (tid < H) {
    float v = pool[0][0][tid] + pool[1][0][tid] + pool[2][0][tid] + pool[3][0][tid];
    atomicAdd(&gsum[g0 * H + tid], v);
    int rlast = bbase + 127; if (rlast > NN - 1) rlast = NN - 1;
    int g1 = batch[rlast];
    if (g1 != g0) {
      float w = pool[0][1][tid] + pool[1][1][tid] + pool[2][1][tid] + pool[3][1][tid];
      atomicAdd(&gsum[g1 * H + tid], w);
    }
  }
}

// ---------------- head ----------------
__global__ void k_head2(const float* __restrict__ gsum, const int* __restrict__ batch,
                        const float* __restrict__ W5, const float* __restrict__ b5,
                        const float* __restrict__ W6, const float* __restrict__ b6,
                        const float* __restrict__ W7, const float* __restrict__ b7,
                        const float* __restrict__ W8, const float* __restrict__ b8,
                        const float* __restrict__ Wl, const float* __restrict__ bl,
                        float* __restrict__ out) {
  __shared__ float s0[128], s1[128];
  __shared__ int sb[2];
  const int g = blockIdx.x, j = threadIdx.x;
  if (j < 2) {  // binary search for bounds of graph g (batch sorted)
    int tgt = g + j, lo = 0, hi = NN;
    while (lo < hi) {
      int mid = (lo + hi) >> 1;
      if (batch[mid] < tgt) lo = mid + 1; else hi = mid;
    }
    sb[j] = lo;
  }
  __syncthreads();
  float cnt = (float)(sb[1] - sb[0]);
  s0[j] = gsum[g * 128 + j] / fmaxf(cnt, 1.f);
  __syncthreads();
  const float* Ws[4] = {W5, W6, W7, W8};
  const float* bs[4] = {b5, b6, b7, b8};
  float* cur = s0;
  float* nxt = s1;
  for (int L = 0; L < 4; ++L) {
    const float* W = Ws[L];
    float a = bs[L][j];
    for (int k = 0; k < 128; ++k) a = fmaf(cur[k], W[k * 128 + j], a);
    nxt[j] = fmaxf(a, 0.f);
    __syncthreads();
    float* t = cur; cur = nxt; nxt = t;
  }
  if (j < 2) {
    float a = bl[j];
    for (int k = 0; k < 128; ++k) a = fmaf(cur[k], Wl[k * 2 + j], a);
    out[g * 2 + j] = 1.f / (1.f + __expf(-a));
  }
}

// ---------------- launch ----------------
static inline char* ws_take(char*& p, size_t bytes) {
  char* r = p;
  p += (bytes + 255) & ~(size_t)255;
  return r;
}

extern "C" void kernel_launch(void* const* d_in, const int* in_sizes, int n_in,
                              void* d_out, int out_size, void* d_ws, size_t ws_size,
                              hipStream_t stream) {
  const float* x0 = (const float*)d_in[0];
  const int* ei = (const int*)d_in[1];
  const int* batch = (const int*)d_in[2];
  const float* Wr[4] = {(const float*)d_in[3], (const float*)d_in[6],
                        (const float*)d_in[9], (const float*)d_in[12]};
  const float* brr[4] = {(const float*)d_in[4], (const float*)d_in[7],
                         (const float*)d_in[10], (const float*)d_in[13]};
  const float* Wo[4] = {(const float*)d_in[5], (const float*)d_in[8],
                        (const float*)d_in[11], (const float*)d_in[14]};
  const float* W5 = (const float*)d_in[15];
  const float* b5 = (const float*)d_in[16];
  const float* W6 = (const float*)d_in[17];
  const float* b6 = (const float*)d_in[18];
  const float* W7 = (const float*)d_in[19];
  const float* b7 = (const float*)d_in[20];
  const float* W8 = (const float*)d_in[21];
  const float* b8 = (const float*)d_in[22];
  const float* Wl = (const float*)d_in[23];
  const float* bl = (const float*)d_in[24];
  float* out = (float*)d_out;

  char* p = (char*)d_ws;
  int* fcnt = (int*)ws_take(p, (size_t)NN * 4);
  int* colp = (int*)ws_take(p, (size_t)NN * DMAX * 4);
  __hip_bfloat16* agg = (__hip_bfloat16*)ws_take(p, (size_t)NN * H * 2);
  unsigned char* f8a = (unsigned char*)ws_take(p, (size_t)(NN + 1) * H);  // fp8 ping
  unsigned char* f8b = (unsigned char*)ws_take(p, (size_t)(NN + 1) * H);  // fp8 pong
  float* gsum = (float*)ws_take(p, (size_t)NG * H * 4);
  __hip_bfloat16* wfall = (__hip_bfloat16*)ws_take(p, 3 * 32768 * 2);
  int* gbase = (int*)ws_take(p, NB * 4);
  __hip_bfloat16* wf1 = wfall;
  __hip_bfloat16* wf2 = wfall + 32768;
  __hip_bfloat16* wf3 = wfall + 65536;
  // pairs buffer (16 MB) aliases agg (25.6 MB): CSR build finishes before the
  // first aggregation write to agg.
  int2* pairs = (int2*)agg;
  (void)ws_size; (void)in_sizes; (void)n_in; (void)out_size;

  k_init_wcvt<<<384 + (NB + NG * H + 64 + 255) / 256, 256, 0, stream>>>(
      gbase, gsum, (unsigned*)(f8a + (size_t)NN * H), (unsigned*)(f8b + (size_t)NN * H),
      Wr[1], Wo[1], Wr[2], Wo[2], Wr[3], Wo[3], wfall);
  k_bucket<<<NBK, 256, 0, stream>>>(ei, gbase, pairs);
  k_fill2<<<NB, 256, 0, stream>>>(pairs, gbase, fcnt, colp);

  // layer 1 (F_IN=4): fused gather + GEMM -> fp8 (R25); also writes sentinels
  k_l1<<<NN / 16, 256, 0, stream>>>(x0, fcnt, colp, Wr[0], Wo[0], brr[0], f8a);

  // layers 2-4: fp8 gather-agg + MFMA GEMM, fp8-only activations ping-pong
  // (R17-R19, R22). Layer 4's GEMM fuses the mean pool (R15/R16).
  k_aggf8<<<6250, 256, 0, stream>>>((const uint2*)f8a, fcnt, colp, (uintx4*)agg);
  k_gemm_mfma<<<782, 256, 0, stream>>>(agg, f8a, wf1, brr[1], f8b);
  k_aggf8<<<6250, 256, 0, stream>>>((const uint2*)f8b, fcnt, colp, (uintx4*)agg);
  k_gemm_mfma<<<782, 256, 0, stream>>>(agg, f8b, wf2, brr[2], f8a);
  k_aggf8<<<6250, 256, 0, stream>>>((const uint2*)f8a, fcnt, colp, (uintx4*)agg);
  k_gemm_mfma_pool<<<782, 256, 0, stream>>>(agg, f8a, wf3, brr[3], batch, gsum);

  // MLP head + sigmoid
  k_head2<<<NG, 128, 0, stream>>>(gsum, batch, W5, b5, W6, b6, W7, b7, W8, b8, Wl, bl, out);
}

// Round 14
// 374.875 us; speedup vs baseline: 1.0265x; 1.0265x over previous
//
#include <hip/hip_runtime.h>
#include <hip/hip_bf16.h>
#include <math.h>

#define NN 100000
#define NE 1600000
#define NG 128
#define H 128
#define DMAX 64   // padded CSR slots/node; P(deg>64 | Poisson16) ~ 1e-17
#define NB 391    // dst-buckets of 256 nodes
#define BCAP 5120 // bucket edge capacity (mean 4092, +16 sigma)
#define EPB 3125  // edges per bucket-build block (512 blocks x 3125 = NE)

typedef __attribute__((ext_vector_type(8))) short short8;
typedef __attribute__((ext_vector_type(4))) float floatx4;
typedef __attribute__((ext_vector_type(2))) float floatx2;
typedef __attribute__((ext_vector_type(4))) int intx4;       // nt-builtin-safe
typedef __attribute__((ext_vector_type(4))) unsigned uintx4; // nt-builtin-safe
typedef __attribute__((ext_vector_type(2))) unsigned uintx2; // nt-builtin-safe

// R21 (do not re-try): fp8 row parity-plane split keyed to bid%8 REGRESSED.
// R23 (do not re-try): 16B/lane gather NULLED (fabric-service-bound).
// R24 (do not re-try): fp8 agg buffer FAILED correctness (quantize-after-sum).
// R22: fp8-only ping-pong activations (e4m3->bf16 exact); absmax 0.0039.
// R25a (kept): MFMA GEMMs prefetch all 24 operand loads before the staging
// barrier (2 waves/SIMD at 64KB LDS exposed ~500cy latency 8x/wave).
// R25b (REVERTED, do not re-try): k_bucket 512->1024 blocks regressed +4us.
// Counters: all-idle, serialization-bound — doubling blocks doubled gbase
// global-atomic contention (400K atomics / 391 addresses) + fixed per-block
// scan/barrier overhead, while the parallel part wasn't the critical path.
// R25c (kept): k_agg4b + k_gemm4 fused into k_l1.

// ---------------- init (gbase/gsum/f8 sentinel rows) + W conversion --------
// R18 layout: wf[t], t = kt*4096 + ct*512 + lane*8 + j  holds the fragment
// element W'[kt*32 + (lane>>4)*8 + j][ct*16 + (lane&15)] — fragments in exact
// read order; also makes the R19 LDS stage a straight linear 64 KB copy.
__global__ void k_init_wcvt(int* __restrict__ gbase, float* __restrict__ gsum,
                            unsigned* __restrict__ rowF8a, unsigned* __restrict__ rowF8b,
                            const float* __restrict__ Wr1, const float* __restrict__ Wo1,
                            const float* __restrict__ Wr2, const float* __restrict__ Wo2,
                            const float* __restrict__ Wr3, const float* __restrict__ Wo3,
                            __hip_bfloat16* __restrict__ wf) {
  if (blockIdx.x < 384) {  // W conversion: 3*32768 elements
    int t = blockIdx.x * 256 + threadIdx.x;
    int L = t >> 15, tt = t & 32767;
    const float* Wr = (L == 0) ? Wr1 : (L == 1) ? Wr2 : Wr3;
    const float* Wo = (L == 0) ? Wo1 : (L == 1) ? Wo2 : Wo3;
    int j = tt & 7, lanex = (tt >> 3) & 63, ct = (tt >> 9) & 7, kt = tt >> 12;
    int lr = lanex & 15, quad = lanex >> 4;
    int n = ct * 16 + lr;
    int r = kt * 32 + quad * 8 + j;
    float v = (r < 128) ? Wr[r * 128 + n] : Wo[(r - 128) * 128 + n];
    wf[t] = __float2bfloat16(v);
  } else {  // init
    int t = (blockIdx.x - 384) * 256 + threadIdx.x;
    if (t < NB) gbase[t] = 0;
    else if (t < NB + NG * H) gsum[t - NB] = 0.f;
    else if (t < NB + NG * H + 32) rowF8a[t - NB - NG * H] = 0u;
    else if (t < NB + NG * H + 64) rowF8b[t - NB - NG * H - 32] = 0u;
  }
}

// ---------------- two-phase CSR build ----------------
// R14: LDS counting-sort so pair-appends are coalesced bursts (~64 B per
// (block,bucket) group) instead of 8 B random scatter (R3-style partial-line
// amplification). One global atomicAdd per (block,bucket). 512 blocks (R25b
// revert: more blocks = more gbase atomic serialization, not more speed).
__global__ __launch_bounds__(256) void k_bucket(const int* __restrict__ ei,
                                                int* __restrict__ gbase,
                                                int2* __restrict__ pairs) {
  __shared__ int scnt[512];   // histogram, padded for scan; reused as fill ctr
  __shared__ int soff[NB];    // local exclusive offsets
  __shared__ int sbase[NB];   // global reserved base
  __shared__ int2 stg[EPB];   // bucket-sorted staging (25 KB)
  __shared__ short sbkt[EPB]; // bucket id per staged edge
  const int tid = threadIdx.x;
  const int e0 = blockIdx.x * EPB;
  const int* dst = ei + NE;

  scnt[tid] = 0;
  scnt[tid + 256] = 0;
  __syncthreads();
  for (int e = e0 + tid; e < e0 + EPB; e += 256) {
    int d = __builtin_nontemporal_load(dst + e);
    atomicAdd(&scnt[d >> 8], 1);
  }
  __syncthreads();
  int c0 = scnt[tid], c1 = scnt[tid + 256];
  // inclusive Hillis-Steele scan over 512 entries (256 threads x 2)
  for (int off = 1; off < 512; off <<= 1) {
    int v0 = (tid >= off) ? scnt[tid - off] : 0;
    int v1 = (tid + 256 >= off) ? scnt[tid + 256 - off] : 0;
    __syncthreads();
    scnt[tid] += v0;
    scnt[tid + 256] += v1;
    __syncthreads();
  }
  if (tid < NB) {
    soff[tid] = scnt[tid] - c0;
    sbase[tid] = c0 ? atomicAdd(&gbase[tid], c0) : 0;
  }
  if (tid + 256 < NB) {
    soff[tid + 256] = scnt[tid + 256] - c1;
    sbase[tid + 256] = c1 ? atomicAdd(&gbase[tid + 256], c1) : 0;
  }
  __syncthreads();
  scnt[tid] = 0;
  scnt[tid + 256] = 0;
  __syncthreads();
  for (int e = e0 + tid; e < e0 + EPB; e += 256) {
    int d = __builtin_nontemporal_load(dst + e);
    int s = __builtin_nontemporal_load(ei + e);
    int b = d >> 8;
    int p = soff[b] + atomicAdd(&scnt[b], 1);
    stg[p] = make_int2(s, d);
    sbkt[p] = (short)b;
  }
  __syncthreads();
  for (int i = tid; i < EPB; i += 256) {
    int b = sbkt[i];
    int gpos = sbase[b] + (i - soff[b]);
    if (gpos < BCAP) pairs[(size_t)b * BCAP + gpos] = stg[i];  // coalesced runs
  }
}

// Phase 2: one block OWNS one 256-dst bucket -> counters in LDS (no global
// atomics), colp slice single-writer, fcnt written directly.
__global__ __launch_bounds__(256) void k_fill2(const int2* __restrict__ pairs,
                                               const int* __restrict__ gbase,
                                               int* __restrict__ fcnt,
                                               int* __restrict__ colp) {
  __shared__ int scnt[256];
  const int b = blockIdx.x;
  const int d0 = b << 8;
  const int tid = threadIdx.x;
  scnt[tid] = 0;
  __syncthreads();
  int n = gbase[b];
  if (n > BCAP) n = BCAP;
  const int2* pp = pairs + (size_t)b * BCAP;
  for (int e = tid; e < n; e += 256) {
    int2 sd = pp[e];  // coalesced
    int dl = sd.y - d0;
    int pos = atomicAdd(&scnt[dl], 1);  // LDS int atomic (native, fast)
    if (pos < DMAX) colp[((size_t)(d0 + dl) << 6) + pos] = sd.x;
  }
  __syncthreads();
  int d = d0 + tid;
  if (d < NN) {
    int c = scnt[tid];
    fcnt[d] = (c > DMAX) ? DMAX : c;
  }
}

// ---------------- bf16/fp8 helpers ----------------
__device__ inline unsigned pk_bf16(float a, float b) {  // RNE pack (lo=a, hi=b)
  unsigned ua = __float_as_uint(a), ub = __float_as_uint(b);
  ua = (ua + 0x7fffu + ((ua >> 16) & 1u)) >> 16;
  ub = (ub + 0x7fffu + ((ub >> 16) & 1u)) & 0xffff0000u;
  return ua | ub;
}

// 8 packed OCP e4m3 (one uint2) dequant + accumulate into fp32[8].
// gfx950 hardware cvt: v_cvt_pk_f32_fp8 (bytes {0,1} sel=0, {2,3} sel=1).
__device__ inline void accf8(float* a, uint2 u) {
  floatx2 p;
  p = __builtin_amdgcn_cvt_pk_f32_fp8((int)u.x, false); a[0] += p.x; a[1] += p.y;
  p = __builtin_amdgcn_cvt_pk_f32_fp8((int)u.x, true);  a[2] += p.x; a[3] += p.y;
  p = __builtin_amdgcn_cvt_pk_f32_fp8((int)u.y, false); a[4] += p.x; a[5] += p.y;
  p = __builtin_amdgcn_cvt_pk_f32_fp8((int)u.y, true);  a[6] += p.x; a[7] += p.y;
}

// 8 packed e4m3 -> 8 bf16 (EXACT: e4m3 values are exactly representable in
// bf16, so f32->bf16 truncation loses nothing).
__device__ inline short8 f8x8_bf16(uintx2 u) {
  floatx2 p0 = __builtin_amdgcn_cvt_pk_f32_fp8((int)u.x, false);
  floatx2 p1 = __builtin_amdgcn_cvt_pk_f32_fp8((int)u.x, true);
  floatx2 p2 = __builtin_amdgcn_cvt_pk_f32_fp8((int)u.y, false);
  floatx2 p3 = __builtin_amdgcn_cvt_pk_f32_fp8((int)u.y, true);
  union { uintx4 u; short8 s; } cv;
  cv.u.x = (__float_as_uint(p0.y) & 0xffff0000u) | (__float_as_uint(p0.x) >> 16);
  cv.u.y = (__float_as_uint(p1.y) & 0xffff0000u) | (__float_as_uint(p1.x) >> 16);
  cv.u.z = (__float_as_uint(p2.y) & 0xffff0000u) | (__float_as_uint(p2.x) >> 16);
  cv.u.w = (__float_as_uint(p3.y) & 0xffff0000u) | (__float_as_uint(p3.x) >> 16);
  return cv.s;
}

// ---------------- aggregation (fp8 gather payload, fp32 acc, bf16 agg) ----
// R17: fp8 e4m3 payload halves the compulsory gather row to 128 B (= exactly
// one L2 line per neighbor). FETCH 95 MB == compulsory model (88.2 gather +
// 6.4 colp + 0.4 fcnt): zero capacity misses, ~86% of fabric line rate.
// At structural floor — do not touch (see R21/R23/R24 notes).
__global__ void k_aggf8(const uint2* __restrict__ xf8, const int* __restrict__ fcnt,
                        const int* __restrict__ colp, uintx4* __restrict__ agg) {
  int w = (blockIdx.x * blockDim.x + threadIdx.x) >> 6;
  int lane = threadIdx.x & 63;
  int qr = lane >> 4, ql = lane & 15;  // qr: node-of-wave, ql: 8B chunk of row
  int node = 4 * w + qr;
  if (node >= NN) return;
  int cnt = fcnt[node];
  cnt = (cnt + 3) & ~3;
  const int* cp = colp + (node << 6);
  float a0[8] = {0}, a1[8] = {0}, a2[8] = {0}, a3[8] = {0};
  for (int i = 0; i < cnt; i += 4) {
    intx4 ss = __builtin_nontemporal_load((const intx4*)(cp + i));
    uint2 u0 = xf8[(size_t)ss.x * 16 + ql];
    uint2 u1 = xf8[(size_t)ss.y * 16 + ql];
    uint2 u2 = xf8[(size_t)ss.z * 16 + ql];
    uint2 u3 = xf8[(size_t)ss.w * 16 + ql];
    accf8(a0, u0);
    accf8(a1, u1);
    accf8(a2, u2);
    accf8(a3, u3);
  }
  float s[8];
#pragma unroll
  for (int t = 0; t < 8; ++t) s[t] = (a0[t] + a1[t]) + (a2[t] + a3[t]);
  uintx4 o;
  o.x = pk_bf16(s[0], s[1]);
  o.y = pk_bf16(s[2], s[3]);
  o.z = pk_bf16(s[4], s[5]);
  o.w = pk_bf16(s[6], s[7]);
  __builtin_nontemporal_store(o, agg + (size_t)node * 16 + ql);
}

// ---------------- layer 1 fused: agg(F_IN=4) + GEMM(K=4+4) -> fp8 ----------
// R25c: k_agg4b + k_gemm4 fused. 16 threads/node: gather neighbors in x-space
// (stride-16), 16-lane butterfly leaves the full agg4 row in every lane,
// then each thread computes 8 output cols. Also writes the <=3 colp sentinel
// slots per node (NN = zeroed row) needed by k_aggf8.
__global__ __launch_bounds__(256) void k_l1(
    const float* __restrict__ x, const int* __restrict__ fcnt,
    int* __restrict__ colp,
    const float* __restrict__ Wr, const float* __restrict__ Wo,
    const float* __restrict__ br, unsigned char* __restrict__ out8) {
  __shared__ float sWr[512], sWo[512], sbr[128];
  const int tid = threadIdx.x;
  sWr[tid] = Wr[tid]; sWr[tid + 256] = Wr[tid + 256];
  sWo[tid] = Wo[tid]; sWo[tid + 256] = Wo[tid + 256];
  if (tid < 128) sbr[tid] = br[tid];

  const int node = blockIdx.x * 16 + (tid >> 4);  // 6250*16 = NN exactly
  const int q = tid & 15;
  const int cnt = fcnt[node];
  // sentinel padding for k_aggf8 (round cnt up to multiple of 4)
  if (q < 4) {
    int up = (cnt + 3) & ~3;
    int pi = cnt + q;
    if (pi < up) colp[(node << 6) + pi] = NN;
  }
  const int* cp = colp + (node << 6);
  float4 acc = make_float4(0.f, 0.f, 0.f, 0.f);
  for (int e = q; e < cnt; e += 16) {
    float4 v = ((const float4*)x)[cp[e]];  // lanes q=0..15 read cp[e..e+15]: coalesced
    acc.x += v.x; acc.y += v.y; acc.z += v.z; acc.w += v.w;
  }
#pragma unroll
  for (int d = 1; d < 16; d <<= 1) {  // 16-lane butterfly: all lanes get the sum
    acc.x += __shfl_xor(acc.x, d);
    acc.y += __shfl_xor(acc.y, d);
    acc.z += __shfl_xor(acc.z, d);
    acc.w += __shfl_xor(acc.w, d);
  }
  float4 xv = ((const float4*)x)[node];  // broadcast across the 16 lanes
  __syncthreads();  // weight staging visible

  const int j0 = q * 8;
  float4 b0 = *(const float4*)&sbr[j0];
  float4 b1 = *(const float4*)&sbr[j0 + 4];
  float v[8] = {b0.x, b0.y, b0.z, b0.w, b1.x, b1.y, b1.z, b1.w};
#pragma unroll
  for (int k = 0; k < 4; ++k) {
    float ak = (k == 0) ? acc.x : (k == 1) ? acc.y : (k == 2) ? acc.z : acc.w;
    float xk = (k == 0) ? xv.x : (k == 1) ? xv.y : (k == 2) ? xv.z : xv.w;
    float4 wr0 = *(const float4*)&sWr[k * 128 + j0];
    float4 wr1 = *(const float4*)&sWr[k * 128 + j0 + 4];
    float4 wo0 = *(const float4*)&sWo[k * 128 + j0];
    float4 wo1 = *(const float4*)&sWo[k * 128 + j0 + 4];
    v[0] = fmaf(ak, wr0.x, fmaf(xk, wo0.x, v[0]));
    v[1] = fmaf(ak, wr0.y, fmaf(xk, wo0.y, v[1]));
    v[2] = fmaf(ak, wr0.z, fmaf(xk, wo0.z, v[2]));
    v[3] = fmaf(ak, wr0.w, fmaf(xk, wo0.w, v[3]));
    v[4] = fmaf(ak, wr1.x, fmaf(xk, wo1.x, v[4]));
    v[5] = fmaf(ak, wr1.y, fmaf(xk, wo1.y, v[5]));
    v[6] = fmaf(ak, wr1.z, fmaf(xk, wo1.z, v[6]));
    v[7] = fmaf(ak, wr1.w, fmaf(xk, wo1.w, v[7]));
  }
#pragma unroll
  for (int jj = 0; jj < 8; ++jj) v[jj] = fmaxf(v[jj], 0.f);
  unsigned w8a, w8b;
  w8a = (unsigned)__builtin_amdgcn_cvt_pk_fp8_f32(v[0], v[1], 0, false);
  w8a = (unsigned)__builtin_amdgcn_cvt_pk_fp8_f32(v[2], v[3], (int)w8a, true);
  w8b = (unsigned)__builtin_amdgcn_cvt_pk_fp8_f32(v[4], v[5], 0, false);
  w8b = (unsigned)__builtin_amdgcn_cvt_pk_fp8_f32(v[6], v[7], (int)w8b, true);
  uint2 o8; o8.x = w8a; o8.y = w8b;
  *(uint2*)(out8 + (size_t)node * H + j0) = o8;
}

// ---------------- MFMA GEMM: relu([agg|x] @ [Wr;Wo] + br) -> fp8 -----------
// R18: operand-swapped MFMA + packed stores. R19: weights staged once per
// block into LDS. R22: X read from fp8 (exact cvt to bf16 fragments).
// R25a: ALL 24 operand loads issued before the staging barrier — at 64KB-LDS
// occupancy (2 waves/SIMD) the old per-kt load->MFMA chain exposed ~500cy
// latency 8x per wave; now 24-deep memory parallelism overlapping staging.
__global__ __launch_bounds__(256) void k_gemm_mfma(
    const __hip_bfloat16* __restrict__ A, const unsigned char* __restrict__ X8,
    const __hip_bfloat16* __restrict__ Wf, const float* __restrict__ br,
    unsigned char* __restrict__ out8) {
  __shared__ short8 sw[4096];  // 64 KB: full [Wr;Wo] fragment tile
  const int tid = threadIdx.x;
  const int wv = tid >> 6, lane = tid & 63;
  const int quad = lane >> 4, lr = lane & 15;
  const int mbase = blockIdx.x * 128 + wv * 32;

  int r0 = mbase + lr;      if (r0 > NN - 1) r0 = NN - 1;
  int r1 = mbase + 16 + lr; if (r1 > NN - 1) r1 = NN - 1;

  // prefetch all operands (R25a)
  short8 a0r[4], a1r[4];
  uintx2 x0r[4], x1r[4];
#pragma unroll
  for (int k = 0; k < 4; ++k) {
    const size_t koff = (size_t)k * 32 + quad * 8;
    a0r[k] = __builtin_nontemporal_load((const short8*)(A + (size_t)r0 * H + koff));
    a1r[k] = __builtin_nontemporal_load((const short8*)(A + (size_t)r1 * H + koff));
  }
#pragma unroll
  for (int k = 0; k < 4; ++k) {
    const size_t koff = (size_t)k * 32 + quad * 8;
    x0r[k] = __builtin_nontemporal_load((const uintx2*)(X8 + (size_t)r0 * H + koff));
    x1r[k] = __builtin_nontemporal_load((const uintx2*)(X8 + (size_t)r1 * H + koff));
  }

#pragma unroll
  for (int i = 0; i < 16; ++i)  // linear 64 KB copy (wf already in read order)
    sw[i * 256 + tid] = ((const short8*)Wf)[i * 256 + tid];

  floatx4 acc[2][8];
#pragma unroll
  for (int rt = 0; rt < 2; ++rt)
#pragma unroll
    for (int ct = 0; ct < 8; ++ct) acc[rt][ct] = (floatx4){0.f, 0.f, 0.f, 0.f};

  __syncthreads();

#pragma unroll
  for (int kt = 0; kt < 8; ++kt) {
    short8 a0 = (kt < 4) ? a0r[kt] : f8x8_bf16(x0r[kt - 4]);
    short8 a1 = (kt < 4) ? a1r[kt] : f8x8_bf16(x1r[kt - 4]);
#pragma unroll
    for (int ct = 0; ct < 8; ++ct) {
      short8 b = sw[kt * 512 + ct * 64 + lane];  // conflict-free ds_read_b128
      // swapped operands: lane lr owns row mbase+rt*16+lr, cols ct*16+quad*4+rg
      acc[0][ct] = __builtin_amdgcn_mfma_f32_16x16x32_bf16(b, a0, acc[0][ct], 0, 0, 0);
      acc[1][ct] = __builtin_amdgcn_mfma_f32_16x16x32_bf16(b, a1, acc[1][ct], 0, 0, 0);
    }
  }

  floatx4 bias4[8];
#pragma unroll
  for (int ct = 0; ct < 8; ++ct)
    bias4[ct] = *(const floatx4*)(br + ct * 16 + quad * 4);

#pragma unroll
  for (int rt = 0; rt < 2; ++rt) {
    int row = mbase + rt * 16 + lr;
    if (row < NN) {
#pragma unroll
      for (int ct = 0; ct < 8; ++ct) {
        float v0 = fmaxf(acc[rt][ct][0] + bias4[ct].x, 0.f);
        float v1 = fmaxf(acc[rt][ct][1] + bias4[ct].y, 0.f);
        float v2 = fmaxf(acc[rt][ct][2] + bias4[ct].z, 0.f);
        float v3 = fmaxf(acc[rt][ct][3] + bias4[ct].w, 0.f);
        unsigned w8 = 0;
        w8 = (unsigned)__builtin_amdgcn_cvt_pk_fp8_f32(v0, v1, (int)w8, false);
        w8 = (unsigned)__builtin_amdgcn_cvt_pk_fp8_f32(v2, v3, (int)w8, true);
        *(unsigned*)(out8 + (size_t)row * H + ct * 16 + quad * 4) = w8;
      }
    }
  }
}

// ---------------- layer-4 MFMA GEMM fused with global mean-pool ------------
// R15: never store x4; pool it in the GEMM epilogue.
// R16: atomic-free epilogue (LDS float atomicAdd lowers to CAS retry loops).
// R19: LDS weight staging. R22: X read from fp8. R25a: operand prefetch.
// Keeps the ORIGINAL operand order (column-per-lane C/D): the pool epilogue
// reduces along rows with a fixed column per lane; no global stores to pack.
__global__ __launch_bounds__(256) void k_gemm_mfma_pool(
    const __hip_bfloat16* __restrict__ A, const unsigned char* __restrict__ X8,
    const __hip_bfloat16* __restrict__ Wf, const float* __restrict__ br,
    const int* __restrict__ batch, float* __restrict__ gsum) {
  __shared__ short8 sw[4096];      // 64 KB weight tile
  __shared__ float pool[4][2][H];  // [wave][segment][column], 4 KB
  const int tid = threadIdx.x;
  const int wv = tid >> 6, lane = tid & 63;
  const int quad = lane >> 4, lr = lane & 15;
  const int bbase = blockIdx.x * 128;
  const int mbase = bbase + wv * 32;

  int r0 = mbase + lr;      if (r0 > NN - 1) r0 = NN - 1;
  int r1 = mbase + 16 + lr; if (r1 > NN - 1) r1 = NN - 1;

  short8 a0r[4], a1r[4];
  uintx2 x0r[4], x1r[4];
#pragma unroll
  for (int k = 0; k < 4; ++k) {
    const size_t koff = (size_t)k * 32 + quad * 8;
    a0r[k] = __builtin_nontemporal_load((const short8*)(A + (size_t)r0 * H + koff));
    a1r[k] = __builtin_nontemporal_load((const short8*)(A + (size_t)r1 * H + koff));
  }
#pragma unroll
  for (int k = 0; k < 4; ++k) {
    const size_t koff = (size_t)k * 32 + quad * 8;
    x0r[k] = __builtin_nontemporal_load((const uintx2*)(X8 + (size_t)r0 * H + koff));
    x1r[k] = __builtin_nontemporal_load((const uintx2*)(X8 + (size_t)r1 * H + koff));
  }

#pragma unroll
  for (int i = 0; i < 16; ++i)
    sw[i * 256 + tid] = ((const short8*)Wf)[i * 256 + tid];

  floatx4 acc[2][8];
#pragma unroll
  for (int rt = 0; rt < 2; ++rt)
#pragma unroll
    for (int ct = 0; ct < 8; ++ct) acc[rt][ct] = (floatx4){0.f, 0.f, 0.f, 0.f};

  __syncthreads();

#pragma unroll
  for (int kt = 0; kt < 8; ++kt) {
    short8 a0 = (kt < 4) ? a0r[kt] : f8x8_bf16(x0r[kt - 4]);
    short8 a1 = (kt < 4) ? a1r[kt] : f8x8_bf16(x1r[kt - 4]);
#pragma unroll
    for (int ct = 0; ct < 8; ++ct) {
      short8 b = sw[kt * 512 + ct * 64 + lane];
      acc[0][ct] = __builtin_amdgcn_mfma_f32_16x16x32_bf16(a0, b, acc[0][ct], 0, 0, 0);
      acc[1][ct] = __builtin_amdgcn_mfma_f32_16x16x32_bf16(a1, b, acc[1][ct], 0, 0, 0);
    }
  }

  const int g0 = batch[bbase];  // block-uniform (bbase <= 99968 < NN)
  float bias[8];
#pragma unroll
  for (int ct = 0; ct < 8; ++ct) bias[ct] = br[ct * 16 + lr];

  // Per-thread segment-split sums over this thread's 8 rows. Static indices
  // only (ps0/ps1 named arrays) so they stay in VGPRs (rule #20).
  float ps0[8] = {0.f, 0.f, 0.f, 0.f, 0.f, 0.f, 0.f, 0.f};
  float ps1[8] = {0.f, 0.f, 0.f, 0.f, 0.f, 0.f, 0.f, 0.f};
#pragma unroll
  for (int rt = 0; rt < 2; ++rt) {
#pragma unroll
    for (int rg = 0; rg < 4; ++rg) {
      int row = mbase + rt * 16 + quad * 4 + rg;
      if (row < NN) {
        if (batch[row] == g0) {
#pragma unroll
          for (int ct = 0; ct < 8; ++ct)
            ps0[ct] += fmaxf(acc[rt][ct][rg] + bias[ct], 0.f);
        } else {
#pragma unroll
          for (int ct = 0; ct < 8; ++ct)
            ps1[ct] += fmaxf(acc[rt][ct][rg] + bias[ct], 0.f);
        }
      }
    }
  }

  // Fold the 4 quads (lanes lr, lr+16, lr+32, lr+48 share column ct*16+lr).
#pragma unroll
  for (int ct = 0; ct < 8; ++ct) {
    float a = ps0[ct];
    a += __shfl_xor(a, 16);
    a += __shfl_xor(a, 32);
    float b = ps1[ct];
    b += __shfl_xor(b, 16);
    b += __shfl_xor(b, 32);
    if (quad == 0) {  // 16 lanes x 8 ct -> full 128-column wave partials
      pool[wv][0][ct * 16 + lr] = a;
      pool[wv][1][ct * 16 + lr] = b;
    }
  }
  __syncthreads();

  if (tid < H) {
    float v = pool[0][0][tid] + pool[1][0][tid] + pool[2][0][tid] + pool[3][0][tid];
    atomicAdd(&gsum[g0 * H + tid], v);
    int rlast = bbase + 127; if (rlast > NN - 1) rlast = NN - 1;
    int g1 = batch[rlast];
    if (g1 != g0) {
      float w = pool[0][1][tid] + pool[1][1][tid] + pool[2][1][tid] + pool[3][1][tid];
      atomicAdd(&gsum[g1 * H + tid], w);
    }
  }
}

// ---------------- head ----------------
__global__ void k_head2(const float* __restrict__ gsum, const int* __restrict__ batch,
                        const float* __restrict__ W5, const float* __restrict__ b5,
                        const float* __restrict__ W6, const float* __restrict__ b6,
                        const float* __restrict__ W7, const float* __restrict__ b7,
                        const float* __restrict__ W8, const float* __restrict__ b8,
                        const float* __restrict__ Wl, const float* __restrict__ bl,
                        float* __restrict__ out) {
  __shared__ float s0[128], s1[128];
  __shared__ int sb[2];
  const int g = blockIdx.x, j = threadIdx.x;
  if (j < 2) {  // binary search for bounds of graph g (batch sorted)
    int tgt = g + j, lo = 0, hi = NN;
    while (lo < hi) {
      int mid = (lo + hi) >> 1;
      if (batch[mid] < tgt) lo = mid + 1; else hi = mid;
    }
    sb[j] = lo;
  }
  __syncthreads();
  float cnt = (float)(sb[1] - sb[0]);
  s0[j] = gsum[g * 128 + j] / fmaxf(cnt, 1.f);
  __syncthreads();
  const float* Ws[4] = {W5, W6, W7, W8};
  const float* bs[4] = {b5, b6, b7, b8};
  float* cur = s0;
  float* nxt = s1;
  for (int L = 0; L < 4; ++L) {
    const float* W = Ws[L];
    float a = bs[L][j];
    for (int k = 0; k < 128; ++k) a = fmaf(cur[k], W[k * 128 + j], a);
    nxt[j] = fmaxf(a, 0.f);
    __syncthreads();
    float* t = cur; cur = nxt; nxt = t;
  }
  if (j < 2) {
    float a = bl[j];
    for (int k = 0; k < 128; ++k) a = fmaf(cur[k], Wl[k * 2 + j], a);
    out[g * 2 + j] = 1.f / (1.f + __expf(-a));
  }
}

// ---------------- launch ----------------
static inline char* ws_take(char*& p, size_t bytes) {
  char* r = p;
  p += (bytes + 255) & ~(size_t)255;
  return r;
}

extern "C" void kernel_launch(void* const* d_in, const int* in_sizes, int n_in,
                              void* d_out, int out_size, void* d_ws, size_t ws_size,
                              hipStream_t stream) {
  const float* x0 = (const float*)d_in[0];
  const int* ei = (const int*)d_in[1];
  const int* batch = (const int*)d_in[2];
  const float* Wr[4] = {(const float*)d_in[3], (const float*)d_in[6],
                        (const float*)d_in[9], (const float*)d_in[12]};
  const float* brr[4] = {(const float*)d_in[4], (const float*)d_in[7],
                         (const float*)d_in[10], (const float*)d_in[13]};
  const float* Wo[4] = {(const float*)d_in[5], (const float*)d_in[8],
                        (const float*)d_in[11], (const float*)d_in[14]};
  const float* W5 = (const float*)d_in[15];
  const float* b5 = (const float*)d_in[16];
  const float* W6 = (const float*)d_in[17];
  const float* b6 = (const float*)d_in[18];
  const float* W7 = (const float*)d_in[19];
  const float* b7 = (const float*)d_in[20];
  const float* W8 = (const float*)d_in[21];
  const float* b8 = (const float*)d_in[22];
  const float* Wl = (const float*)d_in[23];
  const float* bl = (const float*)d_in[24];
  float* out = (float*)d_out;

  char* p = (char*)d_ws;
  int* fcnt = (int*)ws_take(p, (size_t)NN * 4);
  int* colp = (int*)ws_take(p, (size_t)NN * DMAX * 4);
  __hip_bfloat16* agg = (__hip_bfloat16*)ws_take(p, (size_t)NN * H * 2);
  unsigned char* f8a = (unsigned char*)ws_take(p, (size_t)(NN + 1) * H);  // fp8 ping
  unsigned char* f8b = (unsigned char*)ws_take(p, (size_t)(NN + 1) * H);  // fp8 pong
  float* gsum = (float*)ws_take(p, (size_t)NG * H * 4);
  __hip_bfloat16* wfall = (__hip_bfloat16*)ws_take(p, 3 * 32768 * 2);
  int* gbase = (int*)ws_take(p, NB * 4);
  __hip_bfloat16* wf1 = wfall;
  __hip_bfloat16* wf2 = wfall + 32768;
  __hip_bfloat16* wf3 = wfall + 65536;
  // pairs buffer (16 MB) aliases agg (25.6 MB): CSR build finishes before the
  // first aggregation write to agg.
  int2* pairs = (int2*)agg;
  (void)ws_size; (void)in_sizes; (void)n_in; (void)out_size;

  k_init_wcvt<<<384 + (NB + NG * H + 64 + 255) / 256, 256, 0, stream>>>(
      gbase, gsum, (unsigned*)(f8a + (size_t)NN * H), (unsigned*)(f8b + (size_t)NN * H),
      Wr[1], Wo[1], Wr[2], Wo[2], Wr[3], Wo[3], wfall);
  k_bucket<<<512, 256, 0, stream>>>(ei, gbase, pairs);
  k_fill2<<<NB, 256, 0, stream>>>(pairs, gbase, fcnt, colp);

  // layer 1 (F_IN=4): fused gather + GEMM -> fp8 (R25c); also writes sentinels
  k_l1<<<NN / 16, 256, 0, stream>>>(x0, fcnt, colp, Wr[0], Wo[0], brr[0], f8a);

  // layers 2-4: fp8 gather-agg + MFMA GEMM, fp8-only activations ping-pong
  // (R17-R19, R22). Layer 4's GEMM fuses the mean pool (R15/R16).
  k_aggf8<<<6250, 256, 0, stream>>>((const uint2*)f8a, fcnt, colp, (uintx4*)agg);
  k_gemm_mfma<<<782, 256, 0, stream>>>(agg, f8a, wf1, brr[1], f8b);
  k_aggf8<<<6250, 256, 0, stream>>>((const uint2*)f8b, fcnt, colp, (uintx4*)agg);
  k_gemm_mfma<<<782, 256, 0, stream>>>(agg, f8b, wf2, brr[2], f8a);
  k_aggf8<<<6250, 256, 0, stream>>>((const uint2*)f8a, fcnt, colp, (uintx4*)agg);
  k_gemm_mfma_pool<<<782, 256, 0, stream>>>(agg, f8a, wf3, brr[3], batch, gsum);

  // MLP head + sigmoid
  k_head2<<<NG, 128, 0, stream>>>(gsum, batch, W5, b5, W6, b6, W7, b7, W8, b8, Wl, bl, out);
}

// Round 15
// 371.975 us; speedup vs baseline: 1.0345x; 1.0078x over previous
//
#include <hip/hip_runtime.h>
#include <hip/hip_bf16.h>
#include <math.h>

#define NN 100000
#define NE 1600000
#define NG 128
#define H 128
#define DMAX 64   // padded CSR slots/node; P(deg>64 | Poisson16) ~ 1e-17
#define NB 391    // dst-buckets of 256 nodes
#define BCAP 5120 // bucket edge capacity (mean 4092, +16 sigma)
#define EPB 3125  // edges per bucket-build block (512 blocks x 3125 = NE)

typedef __attribute__((ext_vector_type(8))) short short8;
typedef __attribute__((ext_vector_type(4))) float floatx4;
typedef __attribute__((ext_vector_type(2))) float floatx2;
typedef __attribute__((ext_vector_type(4))) int intx4;       // nt-builtin-safe
typedef __attribute__((ext_vector_type(4))) unsigned uintx4; // nt-builtin-safe
typedef __attribute__((ext_vector_type(2))) unsigned uintx2; // nt-builtin-safe

// R21 (do not re-try): fp8 row parity-plane split keyed to bid%8 REGRESSED.
// R23 (do not re-try): 16B/lane gather NULLED (fabric-service-bound).
// R24 (do not re-try): fp8 agg buffer FAILED correctness (quantize-after-sum).
// R25b (do not re-try): k_bucket 1024 blocks regressed (gbase atomic
// serialization + fixed per-block scan overhead; parallel part not critical).
// R22: fp8-only ping-pong activations (e4m3->bf16 exact); absmax 0.0039.
// R25a/c (kept): GEMM operand prefetch; k_l1 fusion.
// R26 (this round): pairs packed to 4 B — u = src | (dl<<17), src<2^17,
// dl=d&255 (8 bits). Halves bucket's pairs store (+ partial-line
// amplification), fill2's read, and the staging LDS (46->33 KB).

// ---------------- init (gbase/gsum/f8 sentinel rows) + W conversion --------
// R18 layout: wf[t], t = kt*4096 + ct*512 + lane*8 + j  holds the fragment
// element W'[kt*32 + (lane>>4)*8 + j][ct*16 + (lane&15)] — fragments in exact
// read order; also makes the R19 LDS stage a straight linear 64 KB copy.
__global__ void k_init_wcvt(int* __restrict__ gbase, float* __restrict__ gsum,
                            unsigned* __restrict__ rowF8a, unsigned* __restrict__ rowF8b,
                            const float* __restrict__ Wr1, const float* __restrict__ Wo1,
                            const float* __restrict__ Wr2, const float* __restrict__ Wo2,
                            const float* __restrict__ Wr3, const float* __restrict__ Wo3,
                            __hip_bfloat16* __restrict__ wf) {
  if (blockIdx.x < 384) {  // W conversion: 3*32768 elements
    int t = blockIdx.x * 256 + threadIdx.x;
    int L = t >> 15, tt = t & 32767;
    const float* Wr = (L == 0) ? Wr1 : (L == 1) ? Wr2 : Wr3;
    const float* Wo = (L == 0) ? Wo1 : (L == 1) ? Wo2 : Wo3;
    int j = tt & 7, lanex = (tt >> 3) & 63, ct = (tt >> 9) & 7, kt = tt >> 12;
    int lr = lanex & 15, quad = lanex >> 4;
    int n = ct * 16 + lr;
    int r = kt * 32 + quad * 8 + j;
    float v = (r < 128) ? Wr[r * 128 + n] : Wo[(r - 128) * 128 + n];
    wf[t] = __float2bfloat16(v);
  } else {  // init
    int t = (blockIdx.x - 384) * 256 + threadIdx.x;
    if (t < NB) gbase[t] = 0;
    else if (t < NB + NG * H) gsum[t - NB] = 0.f;
    else if (t < NB + NG * H + 32) rowF8a[t - NB - NG * H] = 0u;
    else if (t < NB + NG * H + 64) rowF8b[t - NB - NG * H - 32] = 0u;
  }
}

// ---------------- two-phase CSR build ----------------
// R14: LDS counting-sort so pair-appends are coalesced bursts instead of
// random scatter. One global atomicAdd per (block,bucket). 512 blocks.
// R26: 4 B packed pair u = s | (dl<<17).
__global__ __launch_bounds__(256) void k_bucket(const int* __restrict__ ei,
                                                int* __restrict__ gbase,
                                                unsigned* __restrict__ pairs) {
  __shared__ int scnt[512];        // histogram, padded for scan; reused as fill ctr
  __shared__ int soff[NB];         // local exclusive offsets
  __shared__ int sbase[NB];        // global reserved base
  __shared__ unsigned stg[EPB];    // bucket-sorted packed edges (12.5 KB)
  __shared__ short sbkt[EPB];      // bucket id per staged edge
  const int tid = threadIdx.x;
  const int e0 = blockIdx.x * EPB;
  const int* dst = ei + NE;

  scnt[tid] = 0;
  scnt[tid + 256] = 0;
  __syncthreads();
  for (int e = e0 + tid; e < e0 + EPB; e += 256) {
    int d = __builtin_nontemporal_load(dst + e);
    atomicAdd(&scnt[d >> 8], 1);
  }
  __syncthreads();
  int c0 = scnt[tid], c1 = scnt[tid + 256];
  // inclusive Hillis-Steele scan over 512 entries (256 threads x 2)
  for (int off = 1; off < 512; off <<= 1) {
    int v0 = (tid >= off) ? scnt[tid - off] : 0;
    int v1 = (tid + 256 >= off) ? scnt[tid + 256 - off] : 0;
    __syncthreads();
    scnt[tid] += v0;
    scnt[tid + 256] += v1;
    __syncthreads();
  }
  if (tid < NB) {
    soff[tid] = scnt[tid] - c0;
    sbase[tid] = c0 ? atomicAdd(&gbase[tid], c0) : 0;
  }
  if (tid + 256 < NB) {
    soff[tid + 256] = scnt[tid + 256] - c1;
    sbase[tid + 256] = c1 ? atomicAdd(&gbase[tid + 256], c1) : 0;
  }
  __syncthreads();
  scnt[tid] = 0;
  scnt[tid + 256] = 0;
  __syncthreads();
  for (int e = e0 + tid; e < e0 + EPB; e += 256) {
    int d = __builtin_nontemporal_load(dst + e);
    int s = __builtin_nontemporal_load(ei + e);
    int b = d >> 8;
    int p = soff[b] + atomicAdd(&scnt[b], 1);
    stg[p] = (unsigned)s | ((unsigned)(d & 255) << 17);  // R26 pack
    sbkt[p] = (short)b;
  }
  __syncthreads();
  for (int i = tid; i < EPB; i += 256) {
    int b = sbkt[i];
    int gpos = sbase[b] + (i - soff[b]);
    if (gpos < BCAP) pairs[(size_t)b * BCAP + gpos] = stg[i];  // coalesced runs
  }
}

// Phase 2: one block OWNS one 256-dst bucket -> counters in LDS (no global
// atomics), colp slice single-writer, fcnt written directly.
__global__ __launch_bounds__(256) void k_fill2(const unsigned* __restrict__ pairs,
                                               const int* __restrict__ gbase,
                                               int* __restrict__ fcnt,
                                               int* __restrict__ colp) {
  __shared__ int scnt[256];
  const int b = blockIdx.x;
  const int d0 = b << 8;
  const int tid = threadIdx.x;
  scnt[tid] = 0;
  __syncthreads();
  int n = gbase[b];
  if (n > BCAP) n = BCAP;
  const unsigned* pp = pairs + (size_t)b * BCAP;
  for (int e = tid; e < n; e += 256) {
    unsigned u = pp[e];  // coalesced
    int dl = (int)(u >> 17);
    int s = (int)(u & 0x1FFFFu);
    int pos = atomicAdd(&scnt[dl], 1);  // LDS int atomic (native, fast)
    if (pos < DMAX) colp[((size_t)(d0 + dl) << 6) + pos] = s;
  }
  __syncthreads();
  int d = d0 + tid;
  if (d < NN) {
    int c = scnt[tid];
    fcnt[d] = (c > DMAX) ? DMAX : c;
  }
}

// ---------------- bf16/fp8 helpers ----------------
__device__ inline unsigned pk_bf16(float a, float b) {  // RNE pack (lo=a, hi=b)
  unsigned ua = __float_as_uint(a), ub = __float_as_uint(b);
  ua = (ua + 0x7fffu + ((ua >> 16) & 1u)) >> 16;
  ub = (ub + 0x7fffu + ((ub >> 16) & 1u)) & 0xffff0000u;
  return ua | ub;
}

// 8 packed OCP e4m3 (one uint2) dequant + accumulate into fp32[8].
// gfx950 hardware cvt: v_cvt_pk_f32_fp8 (bytes {0,1} sel=0, {2,3} sel=1).
__device__ inline void accf8(float* a, uint2 u) {
  floatx2 p;
  p = __builtin_amdgcn_cvt_pk_f32_fp8((int)u.x, false); a[0] += p.x; a[1] += p.y;
  p = __builtin_amdgcn_cvt_pk_f32_fp8((int)u.x, true);  a[2] += p.x; a[3] += p.y;
  p = __builtin_amdgcn_cvt_pk_f32_fp8((int)u.y, false); a[4] += p.x; a[5] += p.y;
  p = __builtin_amdgcn_cvt_pk_f32_fp8((int)u.y, true);  a[6] += p.x; a[7] += p.y;
}

// 8 packed e4m3 -> 8 bf16 (EXACT: e4m3 values are exactly representable in
// bf16, so f32->bf16 truncation loses nothing).
__device__ inline short8 f8x8_bf16(uintx2 u) {
  floatx2 p0 = __builtin_amdgcn_cvt_pk_f32_fp8((int)u.x, false);
  floatx2 p1 = __builtin_amdgcn_cvt_pk_f32_fp8((int)u.x, true);
  floatx2 p2 = __builtin_amdgcn_cvt_pk_f32_fp8((int)u.y, false);
  floatx2 p3 = __builtin_amdgcn_cvt_pk_f32_fp8((int)u.y, true);
  union { uintx4 u; short8 s; } cv;
  cv.u.x = (__float_as_uint(p0.y) & 0xffff0000u) | (__float_as_uint(p0.x) >> 16);
  cv.u.y = (__float_as_uint(p1.y) & 0xffff0000u) | (__float_as_uint(p1.x) >> 16);
  cv.u.z = (__float_as_uint(p2.y) & 0xffff0000u) | (__float_as_uint(p2.x) >> 16);
  cv.u.w = (__float_as_uint(p3.y) & 0xffff0000u) | (__float_as_uint(p3.x) >> 16);
  return cv.s;
}

// ---------------- aggregation (fp8 gather payload, fp32 acc, bf16 agg) ----
// R17: fp8 e4m3 payload halves the compulsory gather row to 128 B (= exactly
// one L2 line per neighbor). FETCH 95 MB == compulsory model (88.2 gather +
// 6.4 colp + 0.4 fcnt): zero capacity misses, ~86% of fabric line rate.
// At structural floor — do not touch (see R21/R23/R24 notes).
__global__ void k_aggf8(const uint2* __restrict__ xf8, const int* __restrict__ fcnt,
                        const int* __restrict__ colp, uintx4* __restrict__ agg) {
  int w = (blockIdx.x * blockDim.x + threadIdx.x) >> 6;
  int lane = threadIdx.x & 63;
  int qr = lane >> 4, ql = lane & 15;  // qr: node-of-wave, ql: 8B chunk of row
  int node = 4 * w + qr;
  if (node >= NN) return;
  int cnt = fcnt[node];
  cnt = (cnt + 3) & ~3;
  const int* cp = colp + (node << 6);
  float a0[8] = {0}, a1[8] = {0}, a2[8] = {0}, a3[8] = {0};
  for (int i = 0; i < cnt; i += 4) {
    intx4 ss = __builtin_nontemporal_load((const intx4*)(cp + i));
    uint2 u0 = xf8[(size_t)ss.x * 16 + ql];
    uint2 u1 = xf8[(size_t)ss.y * 16 + ql];
    uint2 u2 = xf8[(size_t)ss.z * 16 + ql];
    uint2 u3 = xf8[(size_t)ss.w * 16 + ql];
    accf8(a0, u0);
    accf8(a1, u1);
    accf8(a2, u2);
    accf8(a3, u3);
  }
  float s[8];
#pragma unroll
  for (int t = 0; t < 8; ++t) s[t] = (a0[t] + a1[t]) + (a2[t] + a3[t]);
  uintx4 o;
  o.x = pk_bf16(s[0], s[1]);
  o.y = pk_bf16(s[2], s[3]);
  o.z = pk_bf16(s[4], s[5]);
  o.w = pk_bf16(s[6], s[7]);
  __builtin_nontemporal_store(o, agg + (size_t)node * 16 + ql);
}

// ---------------- layer 1 fused: agg(F_IN=4) + GEMM(K=4+4) -> fp8 ----------
// R25c: k_agg4b + k_gemm4 fused. 16 threads/node: gather neighbors in x-space
// (stride-16), 16-lane butterfly leaves the full agg4 row in every lane,
// then each thread computes 8 output cols. Also writes the <=3 colp sentinel
// slots per node (NN = zeroed row) needed by k_aggf8.
__global__ __launch_bounds__(256) void k_l1(
    const float* __restrict__ x, const int* __restrict__ fcnt,
    int* __restrict__ colp,
    const float* __restrict__ Wr, const float* __restrict__ Wo,
    const float* __restrict__ br, unsigned char* __restrict__ out8) {
  __shared__ float sWr[512], sWo[512], sbr[128];
  const int tid = threadIdx.x;
  sWr[tid] = Wr[tid]; sWr[tid + 256] = Wr[tid + 256];
  sWo[tid] = Wo[tid]; sWo[tid + 256] = Wo[tid + 256];
  if (tid < 128) sbr[tid] = br[tid];

  const int node = blockIdx.x * 16 + (tid >> 4);  // 6250*16 = NN exactly
  const int q = tid & 15;
  const int cnt = fcnt[node];
  // sentinel padding for k_aggf8 (round cnt up to multiple of 4)
  if (q < 4) {
    int up = (cnt + 3) & ~3;
    int pi = cnt + q;
    if (pi < up) colp[(node << 6) + pi] = NN;
  }
  const int* cp = colp + (node << 6);
  float4 acc = make_float4(0.f, 0.f, 0.f, 0.f);
  for (int e = q; e < cnt; e += 16) {
    float4 v = ((const float4*)x)[cp[e]];  // lanes q=0..15 read cp[e..e+15]: coalesced
    acc.x += v.x; acc.y += v.y; acc.z += v.z; acc.w += v.w;
  }
#pragma unroll
  for (int d = 1; d < 16; d <<= 1) {  // 16-lane butterfly: all lanes get the sum
    acc.x += __shfl_xor(acc.x, d);
    acc.y += __shfl_xor(acc.y, d);
    acc.z += __shfl_xor(acc.z, d);
    acc.w += __shfl_xor(acc.w, d);
  }
  float4 xv = ((const float4*)x)[node];  // broadcast across the 16 lanes
  __syncthreads();  // weight staging visible

  const int j0 = q * 8;
  float4 b0 = *(const float4*)&sbr[j0];
  float4 b1 = *(const float4*)&sbr[j0 + 4];
  float v[8] = {b0.x, b0.y, b0.z, b0.w, b1.x, b1.y, b1.z, b1.w};
#pragma unroll
  for (int k = 0; k < 4; ++k) {
    float ak = (k == 0) ? acc.x : (k == 1) ? acc.y : (k == 2) ? acc.z : acc.w;
    float xk = (k == 0) ? xv.x : (k == 1) ? xv.y : (k == 2) ? xv.z : xv.w;
    float4 wr0 = *(const float4*)&sWr[k * 128 + j0];
    float4 wr1 = *(const float4*)&sWr[k * 128 + j0 + 4];
    float4 wo0 = *(const float4*)&sWo[k * 128 + j0];
    float4 wo1 = *(const float4*)&sWo[k * 128 + j0 + 4];
    v[0] = fmaf(ak, wr0.x, fmaf(xk, wo0.x, v[0]));
    v[1] = fmaf(ak, wr0.y, fmaf(xk, wo0.y, v[1]));
    v[2] = fmaf(ak, wr0.z, fmaf(xk, wo0.z, v[2]));
    v[3] = fmaf(ak, wr0.w, fmaf(xk, wo0.w, v[3]));
    v[4] = fmaf(ak, wr1.x, fmaf(xk, wo1.x, v[4]));
    v[5] = fmaf(ak, wr1.y, fmaf(xk, wo1.y, v[5]));
    v[6] = fmaf(ak, wr1.z, fmaf(xk, wo1.z, v[6]));
    v[7] = fmaf(ak, wr1.w, fmaf(xk, wo1.w, v[7]));
  }
#pragma unroll
  for (int jj = 0; jj < 8; ++jj) v[jj] = fmaxf(v[jj], 0.f);
  unsigned w8a, w8b;
  w8a = (unsigned)__builtin_amdgcn_cvt_pk_fp8_f32(v[0], v[1], 0, false);
  w8a = (unsigned)__builtin_amdgcn_cvt_pk_fp8_f32(v[2], v[3], (int)w8a, true);
  w8b = (unsigned)__builtin_amdgcn_cvt_pk_fp8_f32(v[4], v[5], 0, false);
  w8b = (unsigned)__builtin_amdgcn_cvt_pk_fp8_f32(v[6], v[7], (int)w8b, true);
  uint2 o8; o8.x = w8a; o8.y = w8b;
  *(uint2*)(out8 + (size_t)node * H + j0) = o8;
}

// ---------------- MFMA GEMM: relu([agg|x] @ [Wr;Wo] + br) -> fp8 -----------
// R18: operand-swapped MFMA + packed stores. R19: weights staged once per
// block into LDS. R22: X read from fp8 (exact cvt to bf16 fragments).
// R25a: ALL 24 operand loads issued before the staging barrier.
__global__ __launch_bounds__(256) void k_gemm_mfma(
    const __hip_bfloat16* __restrict__ A, const unsigned char* __restrict__ X8,
    const __hip_bfloat16* __restrict__ Wf, const float* __restrict__ br,
    unsigned char* __restrict__ out8) {
  __shared__ short8 sw[4096];  // 64 KB: full [Wr;Wo] fragment tile
  const int tid = threadIdx.x;
  const int wv = tid >> 6, lane = tid & 63;
  const int quad = lane >> 4, lr = lane & 15;
  const int mbase = blockIdx.x * 128 + wv * 32;

  int r0 = mbase + lr;      if (r0 > NN - 1) r0 = NN - 1;
  int r1 = mbase + 16 + lr; if (r1 > NN - 1) r1 = NN - 1;

  // prefetch all operands (R25a)
  short8 a0r[4], a1r[4];
  uintx2 x0r[4], x1r[4];
#pragma unroll
  for (int k = 0; k < 4; ++k) {
    const size_t koff = (size_t)k * 32 + quad * 8;
    a0r[k] = __builtin_nontemporal_load((const short8*)(A + (size_t)r0 * H + koff));
    a1r[k] = __builtin_nontemporal_load((const short8*)(A + (size_t)r1 * H + koff));
  }
#pragma unroll
  for (int k = 0; k < 4; ++k) {
    const size_t koff = (size_t)k * 32 + quad * 8;
    x0r[k] = __builtin_nontemporal_load((const uintx2*)(X8 + (size_t)r0 * H + koff));
    x1r[k] = __builtin_nontemporal_load((const uintx2*)(X8 + (size_t)r1 * H + koff));
  }

#pragma unroll
  for (int i = 0; i < 16; ++i)  // linear 64 KB copy (wf already in read order)
    sw[i * 256 + tid] = ((const short8*)Wf)[i * 256 + tid];

  floatx4 acc[2][8];
#pragma unroll
  for (int rt = 0; rt < 2; ++rt)
#pragma unroll
    for (int ct = 0; ct < 8; ++ct) acc[rt][ct] = (floatx4){0.f, 0.f, 0.f, 0.f};

  __syncthreads();

#pragma unroll
  for (int kt = 0; kt < 8; ++kt) {
    short8 a0 = (kt < 4) ? a0r[kt] : f8x8_bf16(x0r[kt - 4]);
    short8 a1 = (kt < 4) ? a1r[kt] : f8x8_bf16(x1r[kt - 4]);
#pragma unroll
    for (int ct = 0; ct < 8; ++ct) {
      short8 b = sw[kt * 512 + ct * 64 + lane];  // conflict-free ds_read_b128
      // swapped operands: lane lr owns row mbase+rt*16+lr, cols ct*16+quad*4+rg
      acc[0][ct] = __builtin_amdgcn_mfma_f32_16x16x32_bf16(b, a0, acc[0][ct], 0, 0, 0);
      acc[1][ct] = __builtin_amdgcn_mfma_f32_16x16x32_bf16(b, a1, acc[1][ct], 0, 0, 0);
    }
  }

  floatx4 bias4[8];
#pragma unroll
  for (int ct = 0; ct < 8; ++ct)
    bias4[ct] = *(const floatx4*)(br + ct * 16 + quad * 4);

#pragma unroll
  for (int rt = 0; rt < 2; ++rt) {
    int row = mbase + rt * 16 + lr;
    if (row < NN) {
#pragma unroll
      for (int ct = 0; ct < 8; ++ct) {
        float v0 = fmaxf(acc[rt][ct][0] + bias4[ct].x, 0.f);
        float v1 = fmaxf(acc[rt][ct][1] + bias4[ct].y, 0.f);
        float v2 = fmaxf(acc[rt][ct][2] + bias4[ct].z, 0.f);
        float v3 = fmaxf(acc[rt][ct][3] + bias4[ct].w, 0.f);
        unsigned w8 = 0;
        w8 = (unsigned)__builtin_amdgcn_cvt_pk_fp8_f32(v0, v1, (int)w8, false);
        w8 = (unsigned)__builtin_amdgcn_cvt_pk_fp8_f32(v2, v3, (int)w8, true);
        *(unsigned*)(out8 + (size_t)row * H + ct * 16 + quad * 4) = w8;
      }
    }
  }
}

// ---------------- layer-4 MFMA GEMM fused with global mean-pool ------------
// R15: never store x4; pool it in the GEMM epilogue.
// R16: atomic-free epilogue (LDS float atomicAdd lowers to CAS retry loops).
// R19: LDS weight staging. R22: X read from fp8. R25a: operand prefetch.
// Keeps the ORIGINAL operand order (column-per-lane C/D): the pool epilogue
// reduces along rows with a fixed column per lane; no global stores to pack.
__global__ __launch_bounds__(256) void k_gemm_mfma_pool(
    const __hip_bfloat16* __restrict__ A, const unsigned char* __restrict__ X8,
    const __hip_bfloat16* __restrict__ Wf, const float* __restrict__ br,
    const int* __restrict__ batch, float* __restrict__ gsum) {
  __shared__ short8 sw[4096];      // 64 KB weight tile
  __shared__ float pool[4][2][H];  // [wave][segment][column], 4 KB
  const int tid = threadIdx.x;
  const int wv = tid >> 6, lane = tid & 63;
  const int quad = lane >> 4, lr = lane & 15;
  const int bbase = blockIdx.x * 128;
  const int mbase = bbase + wv * 32;

  int r0 = mbase + lr;      if (r0 > NN - 1) r0 = NN - 1;
  int r1 = mbase + 16 + lr; if (r1 > NN - 1) r1 = NN - 1;

  short8 a0r[4], a1r[4];
  uintx2 x0r[4], x1r[4];
#pragma unroll
  for (int k = 0; k < 4; ++k) {
    const size_t koff = (size_t)k * 32 + quad * 8;
    a0r[k] = __builtin_nontemporal_load((const short8*)(A + (size_t)r0 * H + koff));
    a1r[k] = __builtin_nontemporal_load((const short8*)(A + (size_t)r1 * H + koff));
  }
#pragma unroll
  for (int k = 0; k < 4; ++k) {
    const size_t koff = (size_t)k * 32 + quad * 8;
    x0r[k] = __builtin_nontemporal_load((const uintx2*)(X8 + (size_t)r0 * H + koff));
    x1r[k] = __builtin_nontemporal_load((const uintx2*)(X8 + (size_t)r1 * H + koff));
  }

#pragma unroll
  for (int i = 0; i < 16; ++i)
    sw[i * 256 + tid] = ((const short8*)Wf)[i * 256 + tid];

  floatx4 acc[2][8];
#pragma unroll
  for (int rt = 0; rt < 2; ++rt)
#pragma unroll
    for (int ct = 0; ct < 8; ++ct) acc[rt][ct] = (floatx4){0.f, 0.f, 0.f, 0.f};

  __syncthreads();

#pragma unroll
  for (int kt = 0; kt < 8; ++kt) {
    short8 a0 = (kt < 4) ? a0r[kt] : f8x8_bf16(x0r[kt - 4]);
    short8 a1 = (kt < 4) ? a1r[kt] : f8x8_bf16(x1r[kt - 4]);
#pragma unroll
    for (int ct = 0; ct < 8; ++ct) {
      short8 b = sw[kt * 512 + ct * 64 + lane];
      acc[0][ct] = __builtin_amdgcn_mfma_f32_16x16x32_bf16(a0, b, acc[0][ct], 0, 0, 0);
      acc[1][ct] = __builtin_amdgcn_mfma_f32_16x16x32_bf16(a1, b, acc[1][ct], 0, 0, 0);
    }
  }

  const int g0 = batch[bbase];  // block-uniform (bbase <= 99968 < NN)
  float bias[8];
#pragma unroll
  for (int ct = 0; ct < 8; ++ct) bias[ct] = br[ct * 16 + lr];

  // Per-thread segment-split sums over this thread's 8 rows. Static indices
  // only (ps0/ps1 named arrays) so they stay in VGPRs (rule #20).
  float ps0[8] = {0.f, 0.f, 0.f, 0.f, 0.f, 0.f, 0.f, 0.f};
  float ps1[8] = {0.f, 0.f, 0.f, 0.f, 0.f, 0.f, 0.f, 0.f};
#pragma unroll
  for (int rt = 0; rt < 2; ++rt) {
#pragma unroll
    for (int rg = 0; rg < 4; ++rg) {
      int row = mbase + rt * 16 + quad * 4 + rg;
      if (row < NN) {
        if (batch[row] == g0) {
#pragma unroll
          for (int ct = 0; ct < 8; ++ct)
            ps0[ct] += fmaxf(acc[rt][ct][rg] + bias[ct], 0.f);
        } else {
#pragma unroll
          for (int ct = 0; ct < 8; ++ct)
            ps1[ct] += fmaxf(acc[rt][ct][rg] + bias[ct], 0.f);
        }
      }
    }
  }

  // Fold the 4 quads (lanes lr, lr+16, lr+32, lr+48 share column ct*16+lr).
#pragma unroll
  for (int ct = 0; ct < 8; ++ct) {
    float a = ps0[ct];
    a += __shfl_xor(a, 16);
    a += __shfl_xor(a, 32);
    float b = ps1[ct];
    b += __shfl_xor(b, 16);
    b += __shfl_xor(b, 32);
    if (quad == 0) {  // 16 lanes x 8 ct -> full 128-column wave partials
      pool[wv][0][ct * 16 + lr] = a;
      pool[wv][1][ct * 16 + lr] = b;
    }
  }
  __syncthreads();

  if (tid < H) {
    float v = pool[0][0][tid] + pool[1][0][tid] + pool[2][0][tid] + pool[3][0][tid];
    atomicAdd(&gsum[g0 * H + tid], v);
    int rlast = bbase + 127; if (rlast > NN - 1) rlast = NN - 1;
    int g1 = batch[rlast];
    if (g1 != g0) {
      float w = pool[0][1][tid] + pool[1][1][tid] + pool[2][1][tid] + pool[3][1][tid];
      atomicAdd(&gsum[g1 * H + tid], w);
    }
  }
}

// ---------------- head ----------------
__global__ void k_head2(const float* __restrict__ gsum, const int* __restrict__ batch,
                        const float* __restrict__ W5, const float* __restrict__ b5,
                        const float* __restrict__ W6, const float* __restrict__ b6,
                        const float* __restrict__ W7, const float* __restrict__ b7,
                        const float* __restrict__ W8, const float* __restrict__ b8,
                        const float* __restrict__ Wl, const float* __restrict__ bl,
                        float* __restrict__ out) {
  __shared__ float s0[128], s1[128];
  __shared__ int sb[2];
  const int g = blockIdx.x, j = threadIdx.x;
  if (j < 2) {  // binary search for bounds of graph g (batch sorted)
    int tgt = g + j, lo = 0, hi = NN;
    while (lo < hi) {
      int mid = (lo + hi) >> 1;
      if (batch[mid] < tgt) lo = mid + 1; else hi = mid;
    }
    sb[j] = lo;
  }
  __syncthreads();
  float cnt = (float)(sb[1] - sb[0]);
  s0[j] = gsum[g * 128 + j] / fmaxf(cnt, 1.f);
  __syncthreads();
  const float* Ws[4] = {W5, W6, W7, W8};
  const float* bs[4] = {b5, b6, b7, b8};
  float* cur = s0;
  float* nxt = s1;
  for (int L = 0; L < 4; ++L) {
    const float* W = Ws[L];
    float a = bs[L][j];
    for (int k = 0; k < 128; ++k) a = fmaf(cur[k], W[k * 128 + j], a);
    nxt[j] = fmaxf(a, 0.f);
    __syncthreads();
    float* t = cur; cur = nxt; nxt = t;
  }
  if (j < 2) {
    float a = bl[j];
    for (int k = 0; k < 128; ++k) a = fmaf(cur[k], Wl[k * 2 + j], a);
    out[g * 2 + j] = 1.f / (1.f + __expf(-a));
  }
}

// ---------------- launch ----------------
static inline char* ws_take(char*& p, size_t bytes) {
  char* r = p;
  p += (bytes + 255) & ~(size_t)255;
  return r;
}

extern "C" void kernel_launch(void* const* d_in, const int* in_sizes, int n_in,
                              void* d_out, int out_size, void* d_ws, size_t ws_size,
                              hipStream_t stream) {
  const float* x0 = (const float*)d_in[0];
  const int* ei = (const int*)d_in[1];
  const int* batch = (const int*)d_in[2];
  const float* Wr[4] = {(const float*)d_in[3], (const float*)d_in[6],
                        (const float*)d_in[9], (const float*)d_in[12]};
  const float* brr[4] = {(const float*)d_in[4], (const float*)d_in[7],
                         (const float*)d_in[10], (const float*)d_in[13]};
  const float* Wo[4] = {(const float*)d_in[5], (const float*)d_in[8],
                        (const float*)d_in[11], (const float*)d_in[14]};
  const float* W5 = (const float*)d_in[15];
  const float* b5 = (const float*)d_in[16];
  const float* W6 = (const float*)d_in[17];
  const float* b6 = (const float*)d_in[18];
  const float* W7 = (const float*)d_in[19];
  const float* b7 = (const float*)d_in[20];
  const float* W8 = (const float*)d_in[21];
  const float* b8 = (const float*)d_in[22];
  const float* Wl = (const float*)d_in[23];
  const float* bl = (const float*)d_in[24];
  float* out = (float*)d_out;

  char* p = (char*)d_ws;
  int* fcnt = (int*)ws_take(p, (size_t)NN * 4);
  int* colp = (int*)ws_take(p, (size_t)NN * DMAX * 4);
  __hip_bfloat16* agg = (__hip_bfloat16*)ws_take(p, (size_t)NN * H * 2);
  unsigned char* f8a = (unsigned char*)ws_take(p, (size_t)(NN + 1) * H);  // fp8 ping
  unsigned char* f8b = (unsigned char*)ws_take(p, (size_t)(NN + 1) * H);  // fp8 pong
  float* gsum = (float*)ws_take(p, (size_t)NG * H * 4);
  __hip_bfloat16* wfall = (__hip_bfloat16*)ws_take(p, 3 * 32768 * 2);
  int* gbase = (int*)ws_take(p, NB * 4);
  __hip_bfloat16* wf1 = wfall;
  __hip_bfloat16* wf2 = wfall + 32768;
  __hip_bfloat16* wf3 = wfall + 65536;
  // pairs buffer (8 MB, R26 4B-packed) aliases agg (25.6 MB): CSR build
  // finishes before the first aggregation write to agg.
  unsigned* pairs = (unsigned*)agg;
  (void)ws_size; (void)in_sizes; (void)n_in; (void)out_size;

  k_init_wcvt<<<384 + (NB + NG * H + 64 + 255) / 256, 256, 0, stream>>>(
      gbase, gsum, (unsigned*)(f8a + (size_t)NN * H), (unsigned*)(f8b + (size_t)NN * H),
      Wr[1], Wo[1], Wr[2], Wo[2], Wr[3], Wo[3], wfall);
  k_bucket<<<512, 256, 0, stream>>>(ei, gbase, pairs);
  k_fill2<<<NB, 256, 0, stream>>>(pairs, gbase, fcnt, colp);

  // layer 1 (F_IN=4): fused gather + GEMM -> fp8 (R25c); also writes sentinels
  k_l1<<<NN / 16, 256, 0, stream>>>(x0, fcnt, colp, Wr[0], Wo[0], brr[0], f8a);

  // layers 2-4: fp8 gather-agg + MFMA GEMM, fp8-only activations ping-pong
  // (R17-R19, R22). Layer 4's GEMM fuses the mean pool (R15/R16).
  k_aggf8<<<6250, 256, 0, stream>>>((const uint2*)f8a, fcnt, colp, (uintx4*)agg);
  k_gemm_mfma<<<782, 256, 0, stream>>>(agg, f8a, wf1, brr[1], f8b);
  k_aggf8<<<6250, 256, 0, stream>>>((const uint2*)f8b, fcnt, colp, (uintx4*)agg);
  k_gemm_mfma<<<782, 256, 0, stream>>>(agg, f8b, wf2, brr[2], f8a);
  k_aggf8<<<6250, 256, 0, stream>>>((const uint2*)f8a, fcnt, colp, (uintx4*)agg);
  k_gemm_mfma_pool<<<782, 256, 0, stream>>>(agg, f8a, wf3, brr[3], batch, gsum);

  // MLP head + sigmoid
  k_head2<<<NG, 128, 0, stream>>>(gsum, batch, W5, b5, W6, b6, W7, b7, W8, b8, Wl, bl, out);
}

// Round 16
// 365.097 us; speedup vs baseline: 1.0540x; 1.0188x over previous
//
#include <hip/hip_runtime.h>
#include <hip/hip_bf16.h>
#include <math.h>

#define NN 100000
#define NE 1600000
#define NG 128
#define H 128
#define DMAX 64   // padded CSR slots/node; P(deg>64 | Poisson16) ~ 1e-17
#define NB 391    // dst-buckets of 256 nodes
#define BCAP 5120 // bucket edge capacity (mean 4092, +16 sigma)
#define EPB 3125  // edges per bucket-build block (512 blocks x 3125 = NE)

typedef __attribute__((ext_vector_type(8))) short short8;
typedef __attribute__((ext_vector_type(4))) float floatx4;
typedef __attribute__((ext_vector_type(2))) float floatx2;
typedef __attribute__((ext_vector_type(4))) int intx4;       // nt-builtin-safe
typedef __attribute__((ext_vector_type(4))) unsigned uintx4; // nt-builtin-safe
typedef __attribute__((ext_vector_type(2))) unsigned uintx2; // nt-builtin-safe

// R21 (do not re-try): fp8 row parity-plane split keyed to bid%8 REGRESSED.
// R23 (do not re-try): 16B/lane gather NULLED (fabric-service-bound).
// R24 (do not re-try): fp8 agg buffer FAILED correctness (quantize-after-sum).
// R25b (do not re-try): k_bucket 1024 blocks regressed (gbase atomic
// serialization + fixed per-block scan overhead).
// R22: fp8-only ping-pong activations (e4m3->bf16 exact); absmax 0.0039.
// R25c (kept): k_l1 fusion. R26 (kept): 4B packed pairs.
// R27 (this round): MFMA GEMMs moved to 512-thread blocks / 256-row tiles,
// same 64KB weight tile -> 16 waves/CU (4/SIMD) instead of 8 (2/SIMD), 2x
// TLP at zero extra staging traffic (grid halves). R25a register prefetch
// REMOVED (measured ~neutral; cutting it keeps VGPR low enough for the
// doubled wave count).

// ---------------- init (gbase/gsum/f8 sentinel rows) + W conversion --------
// R18 layout: wf[t], t = kt*4096 + ct*512 + lane*8 + j  holds the fragment
// element W'[kt*32 + (lane>>4)*8 + j][ct*16 + (lane&15)] — fragments in exact
// read order; also makes the R19 LDS stage a straight linear 64 KB copy.
__global__ void k_init_wcvt(int* __restrict__ gbase, float* __restrict__ gsum,
                            unsigned* __restrict__ rowF8a, unsigned* __restrict__ rowF8b,
                            const float* __restrict__ Wr1, const float* __restrict__ Wo1,
                            const float* __restrict__ Wr2, const float* __restrict__ Wo2,
                            const float* __restrict__ Wr3, const float* __restrict__ Wo3,
                            __hip_bfloat16* __restrict__ wf) {
  if (blockIdx.x < 384) {  // W conversion: 3*32768 elements
    int t = blockIdx.x * 256 + threadIdx.x;
    int L = t >> 15, tt = t & 32767;
    const float* Wr = (L == 0) ? Wr1 : (L == 1) ? Wr2 : Wr3;
    const float* Wo = (L == 0) ? Wo1 : (L == 1) ? Wo2 : Wo3;
    int j = tt & 7, lanex = (tt >> 3) & 63, ct = (tt >> 9) & 7, kt = tt >> 12;
    int lr = lanex & 15, quad = lanex >> 4;
    int n = ct * 16 + lr;
    int r = kt * 32 + quad * 8 + j;
    float v = (r < 128) ? Wr[r * 128 + n] : Wo[(r - 128) * 128 + n];
    wf[t] = __float2bfloat16(v);
  } else {  // init
    int t = (blockIdx.x - 384) * 256 + threadIdx.x;
    if (t < NB) gbase[t] = 0;
    else if (t < NB + NG * H) gsum[t - NB] = 0.f;
    else if (t < NB + NG * H + 32) rowF8a[t - NB - NG * H] = 0u;
    else if (t < NB + NG * H + 64) rowF8b[t - NB - NG * H - 32] = 0u;
  }
}

// ---------------- two-phase CSR build ----------------
// R14: LDS counting-sort so pair-appends are coalesced bursts instead of
// random scatter. One global atomicAdd per (block,bucket). 512 blocks.
// R26: 4 B packed pair u = s | (dl<<17).
__global__ __launch_bounds__(256) void k_bucket(const int* __restrict__ ei,
                                                int* __restrict__ gbase,
                                                unsigned* __restrict__ pairs) {
  __shared__ int scnt[512];        // histogram, padded for scan; reused as fill ctr
  __shared__ int soff[NB];         // local exclusive offsets
  __shared__ int sbase[NB];        // global reserved base
  __shared__ unsigned stg[EPB];    // bucket-sorted packed edges (12.5 KB)
  __shared__ short sbkt[EPB];      // bucket id per staged edge
  const int tid = threadIdx.x;
  const int e0 = blockIdx.x * EPB;
  const int* dst = ei + NE;

  scnt[tid] = 0;
  scnt[tid + 256] = 0;
  __syncthreads();
  for (int e = e0 + tid; e < e0 + EPB; e += 256) {
    int d = __builtin_nontemporal_load(dst + e);
    atomicAdd(&scnt[d >> 8], 1);
  }
  __syncthreads();
  int c0 = scnt[tid], c1 = scnt[tid + 256];
  // inclusive Hillis-Steele scan over 512 entries (256 threads x 2)
  for (int off = 1; off < 512; off <<= 1) {
    int v0 = (tid >= off) ? scnt[tid - off] : 0;
    int v1 = (tid + 256 >= off) ? scnt[tid + 256 - off] : 0;
    __syncthreads();
    scnt[tid] += v0;
    scnt[tid + 256] += v1;
    __syncthreads();
  }
  if (tid < NB) {
    soff[tid] = scnt[tid] - c0;
    sbase[tid] = c0 ? atomicAdd(&gbase[tid], c0) : 0;
  }
  if (tid + 256 < NB) {
    soff[tid + 256] = scnt[tid + 256] - c1;
    sbase[tid + 256] = c1 ? atomicAdd(&gbase[tid + 256], c1) : 0;
  }
  __syncthreads();
  scnt[tid] = 0;
  scnt[tid + 256] = 0;
  __syncthreads();
  for (int e = e0 + tid; e < e0 + EPB; e += 256) {
    int d = __builtin_nontemporal_load(dst + e);
    int s = __builtin_nontemporal_load(ei + e);
    int b = d >> 8;
    int p = soff[b] + atomicAdd(&scnt[b], 1);
    stg[p] = (unsigned)s | ((unsigned)(d & 255) << 17);  // R26 pack
    sbkt[p] = (short)b;
  }
  __syncthreads();
  for (int i = tid; i < EPB; i += 256) {
    int b = sbkt[i];
    int gpos = sbase[b] + (i - soff[b]);
    if (gpos < BCAP) pairs[(size_t)b * BCAP + gpos] = stg[i];  // coalesced runs
  }
}

// Phase 2: one block OWNS one 256-dst bucket -> counters in LDS (no global
// atomics), colp slice single-writer, fcnt written directly.
__global__ __launch_bounds__(256) void k_fill2(const unsigned* __restrict__ pairs,
                                               const int* __restrict__ gbase,
                                               int* __restrict__ fcnt,
                                               int* __restrict__ colp) {
  __shared__ int scnt[256];
  const int b = blockIdx.x;
  const int d0 = b << 8;
  const int tid = threadIdx.x;
  scnt[tid] = 0;
  __syncthreads();
  int n = gbase[b];
  if (n > BCAP) n = BCAP;
  const unsigned* pp = pairs + (size_t)b * BCAP;
  for (int e = tid; e < n; e += 256) {
    unsigned u = pp[e];  // coalesced
    int dl = (int)(u >> 17);
    int s = (int)(u & 0x1FFFFu);
    int pos = atomicAdd(&scnt[dl], 1);  // LDS int atomic (native, fast)
    if (pos < DMAX) colp[((size_t)(d0 + dl) << 6) + pos] = s;
  }
  __syncthreads();
  int d = d0 + tid;
  if (d < NN) {
    int c = scnt[tid];
    fcnt[d] = (c > DMAX) ? DMAX : c;
  }
}

// ---------------- bf16/fp8 helpers ----------------
__device__ inline unsigned pk_bf16(float a, float b) {  // RNE pack (lo=a, hi=b)
  unsigned ua = __float_as_uint(a), ub = __float_as_uint(b);
  ua = (ua + 0x7fffu + ((ua >> 16) & 1u)) >> 16;
  ub = (ub + 0x7fffu + ((ub >> 16) & 1u)) & 0xffff0000u;
  return ua | ub;
}

// 8 packed OCP e4m3 (one uint2) dequant + accumulate into fp32[8].
// gfx950 hardware cvt: v_cvt_pk_f32_fp8 (bytes {0,1} sel=0, {2,3} sel=1).
__device__ inline void accf8(float* a, uint2 u) {
  floatx2 p;
  p = __builtin_amdgcn_cvt_pk_f32_fp8((int)u.x, false); a[0] += p.x; a[1] += p.y;
  p = __builtin_amdgcn_cvt_pk_f32_fp8((int)u.x, true);  a[2] += p.x; a[3] += p.y;
  p = __builtin_amdgcn_cvt_pk_f32_fp8((int)u.y, false); a[4] += p.x; a[5] += p.y;
  p = __builtin_amdgcn_cvt_pk_f32_fp8((int)u.y, true);  a[6] += p.x; a[7] += p.y;
}

// 8 packed e4m3 -> 8 bf16 (EXACT: e4m3 values are exactly representable in
// bf16, so f32->bf16 truncation loses nothing).
__device__ inline short8 f8x8_bf16(uintx2 u) {
  floatx2 p0 = __builtin_amdgcn_cvt_pk_f32_fp8((int)u.x, false);
  floatx2 p1 = __builtin_amdgcn_cvt_pk_f32_fp8((int)u.x, true);
  floatx2 p2 = __builtin_amdgcn_cvt_pk_f32_fp8((int)u.y, false);
  floatx2 p3 = __builtin_amdgcn_cvt_pk_f32_fp8((int)u.y, true);
  union { uintx4 u; short8 s; } cv;
  cv.u.x = (__float_as_uint(p0.y) & 0xffff0000u) | (__float_as_uint(p0.x) >> 16);
  cv.u.y = (__float_as_uint(p1.y) & 0xffff0000u) | (__float_as_uint(p1.x) >> 16);
  cv.u.z = (__float_as_uint(p2.y) & 0xffff0000u) | (__float_as_uint(p2.x) >> 16);
  cv.u.w = (__float_as_uint(p3.y) & 0xffff0000u) | (__float_as_uint(p3.x) >> 16);
  return cv.s;
}

// ---------------- aggregation (fp8 gather payload, fp32 acc, bf16 agg) ----
// R17: fp8 e4m3 payload halves the compulsory gather row to 128 B (= exactly
// one L2 line per neighbor). FETCH 95 MB == compulsory model (88.2 gather +
// 6.4 colp + 0.4 fcnt): zero capacity misses, ~86% of fabric line rate.
// At structural floor — do not touch (see R21/R23/R24 notes).
__global__ void k_aggf8(const uint2* __restrict__ xf8, const int* __restrict__ fcnt,
                        const int* __restrict__ colp, uintx4* __restrict__ agg) {
  int w = (blockIdx.x * blockDim.x + threadIdx.x) >> 6;
  int lane = threadIdx.x & 63;
  int qr = lane >> 4, ql = lane & 15;  // qr: node-of-wave, ql: 8B chunk of row
  int node = 4 * w + qr;
  if (node >= NN) return;
  int cnt = fcnt[node];
  cnt = (cnt + 3) & ~3;
  const int* cp = colp + (node << 6);
  float a0[8] = {0}, a1[8] = {0}, a2[8] = {0}, a3[8] = {0};
  for (int i = 0; i < cnt; i += 4) {
    intx4 ss = __builtin_nontemporal_load((const intx4*)(cp + i));
    uint2 u0 = xf8[(size_t)ss.x * 16 + ql];
    uint2 u1 = xf8[(size_t)ss.y * 16 + ql];
    uint2 u2 = xf8[(size_t)ss.z * 16 + ql];
    uint2 u3 = xf8[(size_t)ss.w * 16 + ql];
    accf8(a0, u0);
    accf8(a1, u1);
    accf8(a2, u2);
    accf8(a3, u3);
  }
  float s[8];
#pragma unroll
  for (int t = 0; t < 8; ++t) s[t] = (a0[t] + a1[t]) + (a2[t] + a3[t]);
  uintx4 o;
  o.x = pk_bf16(s[0], s[1]);
  o.y = pk_bf16(s[2], s[3]);
  o.z = pk_bf16(s[4], s[5]);
  o.w = pk_bf16(s[6], s[7]);
  __builtin_nontemporal_store(o, agg + (size_t)node * 16 + ql);
}

// ---------------- layer 1 fused: agg(F_IN=4) + GEMM(K=4+4) -> fp8 ----------
// R25c: k_agg4b + k_gemm4 fused. 16 threads/node: gather neighbors in x-space
// (stride-16), 16-lane butterfly leaves the full agg4 row in every lane,
// then each thread computes 8 output cols. Also writes the <=3 colp sentinel
// slots per node (NN = zeroed row) needed by k_aggf8.
__global__ __launch_bounds__(256) void k_l1(
    const float* __restrict__ x, const int* __restrict__ fcnt,
    int* __restrict__ colp,
    const float* __restrict__ Wr, const float* __restrict__ Wo,
    const float* __restrict__ br, unsigned char* __restrict__ out8) {
  __shared__ float sWr[512], sWo[512], sbr[128];
  const int tid = threadIdx.x;
  sWr[tid] = Wr[tid]; sWr[tid + 256] = Wr[tid + 256];
  sWo[tid] = Wo[tid]; sWo[tid + 256] = Wo[tid + 256];
  if (tid < 128) sbr[tid] = br[tid];

  const int node = blockIdx.x * 16 + (tid >> 4);  // 6250*16 = NN exactly
  const int q = tid & 15;
  const int cnt = fcnt[node];
  // sentinel padding for k_aggf8 (round cnt up to multiple of 4)
  if (q < 4) {
    int up = (cnt + 3) & ~3;
    int pi = cnt + q;
    if (pi < up) colp[(node << 6) + pi] = NN;
  }
  const int* cp = colp + (node << 6);
  float4 acc = make_float4(0.f, 0.f, 0.f, 0.f);
  for (int e = q; e < cnt; e += 16) {
    float4 v = ((const float4*)x)[cp[e]];  // lanes q=0..15 read cp[e..e+15]: coalesced
    acc.x += v.x; acc.y += v.y; acc.z += v.z; acc.w += v.w;
  }
#pragma unroll
  for (int d = 1; d < 16; d <<= 1) {  // 16-lane butterfly: all lanes get the sum
    acc.x += __shfl_xor(acc.x, d);
    acc.y += __shfl_xor(acc.y, d);
    acc.z += __shfl_xor(acc.z, d);
    acc.w += __shfl_xor(acc.w, d);
  }
  float4 xv = ((const float4*)x)[node];  // broadcast across the 16 lanes
  __syncthreads();  // weight staging visible

  const int j0 = q * 8;
  float4 b0 = *(const float4*)&sbr[j0];
  float4 b1 = *(const float4*)&sbr[j0 + 4];
  float v[8] = {b0.x, b0.y, b0.z, b0.w, b1.x, b1.y, b1.z, b1.w};
#pragma unroll
  for (int k = 0; k < 4; ++k) {
    float ak = (k == 0) ? acc.x : (k == 1) ? acc.y : (k == 2) ? acc.z : acc.w;
    float xk = (k == 0) ? xv.x : (k == 1) ? xv.y : (k == 2) ? xv.z : xv.w;
    float4 wr0 = *(const float4*)&sWr[k * 128 + j0];
    float4 wr1 = *(const float4*)&sWr[k * 128 + j0 + 4];
    float4 wo0 = *(const float4*)&sWo[k * 128 + j0];
    float4 wo1 = *(const float4*)&sWo[k * 128 + j0 + 4];
    v[0] = fmaf(ak, wr0.x, fmaf(xk, wo0.x, v[0]));
    v[1] = fmaf(ak, wr0.y, fmaf(xk, wo0.y, v[1]));
    v[2] = fmaf(ak, wr0.z, fmaf(xk, wo0.z, v[2]));
    v[3] = fmaf(ak, wr0.w, fmaf(xk, wo0.w, v[3]));
    v[4] = fmaf(ak, wr1.x, fmaf(xk, wo1.x, v[4]));
    v[5] = fmaf(ak, wr1.y, fmaf(xk, wo1.y, v[5]));
    v[6] = fmaf(ak, wr1.z, fmaf(xk, wo1.z, v[6]));
    v[7] = fmaf(ak, wr1.w, fmaf(xk, wo1.w, v[7]));
  }
#pragma unroll
  for (int jj = 0; jj < 8; ++jj) v[jj] = fmaxf(v[jj], 0.f);
  unsigned w8a, w8b;
  w8a = (unsigned)__builtin_amdgcn_cvt_pk_fp8_f32(v[0], v[1], 0, false);
  w8a = (unsigned)__builtin_amdgcn_cvt_pk_fp8_f32(v[2], v[3], (int)w8a, true);
  w8b = (unsigned)__builtin_amdgcn_cvt_pk_fp8_f32(v[4], v[5], 0, false);
  w8b = (unsigned)__builtin_amdgcn_cvt_pk_fp8_f32(v[6], v[7], (int)w8b, true);
  uint2 o8; o8.x = w8a; o8.y = w8b;
  *(uint2*)(out8 + (size_t)node * H + j0) = o8;
}

// ---------------- MFMA GEMM: relu([agg|x] @ [Wr;Wo] + br) -> fp8 -----------
// R18: operand-swapped MFMA + packed stores. R19: weights staged once per
// block into LDS. R22: X read from fp8 (exact cvt to bf16 fragments).
// R27: 512-thread blocks / 256-row tiles, same 64 KB weight tile -> 16
// waves/CU (4/SIMD) vs 8; per-kt load loop restored (prefetch removed to
// keep VGPR low for the doubled wave count).
__global__ __launch_bounds__(512) void k_gemm_mfma(
    const __hip_bfloat16* __restrict__ A, const unsigned char* __restrict__ X8,
    const __hip_bfloat16* __restrict__ Wf, const float* __restrict__ br,
    unsigned char* __restrict__ out8) {
  __shared__ short8 sw[4096];  // 64 KB: full [Wr;Wo] fragment tile
  const int tid = threadIdx.x;
  const int wv = tid >> 6, lane = tid & 63;
  const int quad = lane >> 4, lr = lane & 15;
  const int mbase = blockIdx.x * 256 + wv * 32;

#pragma unroll
  for (int i = 0; i < 8; ++i)  // linear 64 KB copy (wf already in read order)
    sw[i * 512 + tid] = ((const short8*)Wf)[i * 512 + tid];

  floatx4 acc[2][8];
#pragma unroll
  for (int rt = 0; rt < 2; ++rt)
#pragma unroll
    for (int ct = 0; ct < 8; ++ct) acc[rt][ct] = (floatx4){0.f, 0.f, 0.f, 0.f};

  int r0 = mbase + lr;      if (r0 > NN - 1) r0 = NN - 1;
  int r1 = mbase + 16 + lr; if (r1 > NN - 1) r1 = NN - 1;

  __syncthreads();

#pragma unroll
  for (int kt = 0; kt < 8; ++kt) {
    const size_t koff = (size_t)(kt & 3) * 32 + quad * 8;
    short8 a0, a1;
    if (kt < 4) {  // agg operand: bf16
      a0 = __builtin_nontemporal_load((const short8*)(A + (size_t)r0 * H + koff));
      a1 = __builtin_nontemporal_load((const short8*)(A + (size_t)r1 * H + koff));
    } else {       // root operand: fp8 -> bf16 (exact)
      a0 = f8x8_bf16(__builtin_nontemporal_load((const uintx2*)(X8 + (size_t)r0 * H + koff)));
      a1 = f8x8_bf16(__builtin_nontemporal_load((const uintx2*)(X8 + (size_t)r1 * H + koff)));
    }
#pragma unroll
    for (int ct = 0; ct < 8; ++ct) {
      short8 b = sw[kt * 512 + ct * 64 + lane];  // conflict-free ds_read_b128
      // swapped operands: lane lr owns row mbase+rt*16+lr, cols ct*16+quad*4+rg
      acc[0][ct] = __builtin_amdgcn_mfma_f32_16x16x32_bf16(b, a0, acc[0][ct], 0, 0, 0);
      acc[1][ct] = __builtin_amdgcn_mfma_f32_16x16x32_bf16(b, a1, acc[1][ct], 0, 0, 0);
    }
  }

  floatx4 bias4[8];
#pragma unroll
  for (int ct = 0; ct < 8; ++ct)
    bias4[ct] = *(const floatx4*)(br + ct * 16 + quad * 4);

#pragma unroll
  for (int rt = 0; rt < 2; ++rt) {
    int row = mbase + rt * 16 + lr;
    if (row < NN) {
#pragma unroll
      for (int ct = 0; ct < 8; ++ct) {
        float v0 = fmaxf(acc[rt][ct][0] + bias4[ct].x, 0.f);
        float v1 = fmaxf(acc[rt][ct][1] + bias4[ct].y, 0.f);
        float v2 = fmaxf(acc[rt][ct][2] + bias4[ct].z, 0.f);
        float v3 = fmaxf(acc[rt][ct][3] + bias4[ct].w, 0.f);
        unsigned w8 = 0;
        w8 = (unsigned)__builtin_amdgcn_cvt_pk_fp8_f32(v0, v1, (int)w8, false);
        w8 = (unsigned)__builtin_amdgcn_cvt_pk_fp8_f32(v2, v3, (int)w8, true);
        *(unsigned*)(out8 + (size_t)row * H + ct * 16 + quad * 4) = w8;
      }
    }
  }
}

// ---------------- layer-4 MFMA GEMM fused with global mean-pool ------------
// R15: never store x4; pool it in the GEMM epilogue.
// R16: atomic-free epilogue (LDS float atomicAdd lowers to CAS retry loops).
// R19: LDS weight staging. R22: X read from fp8. R27: 512 threads/256 rows.
// 256-row window still spans <=2 graphs (min graph ~670 >> 256). Keeps the
// ORIGINAL operand order (column-per-lane C/D): the pool epilogue reduces
// along rows with a fixed column per lane; no global stores to pack.
__global__ __launch_bounds__(512) void k_gemm_mfma_pool(
    const __hip_bfloat16* __restrict__ A, const unsigned char* __restrict__ X8,
    const __hip_bfloat16* __restrict__ Wf, const float* __restrict__ br,
    const int* __restrict__ batch, float* __restrict__ gsum) {
  __shared__ short8 sw[4096];      // 64 KB weight tile
  __shared__ float pool[8][2][H];  // [wave][segment][column], 8 KB
  const int tid = threadIdx.x;
  const int wv = tid >> 6, lane = tid & 63;
  const int quad = lane >> 4, lr = lane & 15;
  const int bbase = blockIdx.x * 256;
  const int mbase = bbase + wv * 32;

#pragma unroll
  for (int i = 0; i < 8; ++i)
    sw[i * 512 + tid] = ((const short8*)Wf)[i * 512 + tid];

  floatx4 acc[2][8];
#pragma unroll
  for (int rt = 0; rt < 2; ++rt)
#pragma unroll
    for (int ct = 0; ct < 8; ++ct) acc[rt][ct] = (floatx4){0.f, 0.f, 0.f, 0.f};

  int r0 = mbase + lr;      if (r0 > NN - 1) r0 = NN - 1;
  int r1 = mbase + 16 + lr; if (r1 > NN - 1) r1 = NN - 1;

  __syncthreads();

#pragma unroll
  for (int kt = 0; kt < 8; ++kt) {
    const size_t koff = (size_t)(kt & 3) * 32 + quad * 8;
    short8 a0, a1;
    if (kt < 4) {
      a0 = __builtin_nontemporal_load((const short8*)(A + (size_t)r0 * H + koff));
      a1 = __builtin_nontemporal_load((const short8*)(A + (size_t)r1 * H + koff));
    } else {
      a0 = f8x8_bf16(__builtin_nontemporal_load((const uintx2*)(X8 + (size_t)r0 * H + koff)));
      a1 = f8x8_bf16(__builtin_nontemporal_load((const uintx2*)(X8 + (size_t)r1 * H + koff)));
    }
#pragma unroll
    for (int ct = 0; ct < 8; ++ct) {
      short8 b = sw[kt * 512 + ct * 64 + lane];
      acc[0][ct] = __builtin_amdgcn_mfma_f32_16x16x32_bf16(a0, b, acc[0][ct], 0, 0, 0);
      acc[1][ct] = __builtin_amdgcn_mfma_f32_16x16x32_bf16(a1, b, acc[1][ct], 0, 0, 0);
    }
  }

  const int g0 = batch[bbase];  // block-uniform (bbase <= 99840 < NN)
  float bias[8];
#pragma unroll
  for (int ct = 0; ct < 8; ++ct) bias[ct] = br[ct * 16 + lr];

  // Per-thread segment-split sums over this thread's 8 rows. Static indices
  // only (ps0/ps1 named arrays) so they stay in VGPRs (rule #20).
  float ps0[8] = {0.f, 0.f, 0.f, 0.f, 0.f, 0.f, 0.f, 0.f};
  float ps1[8] = {0.f, 0.f, 0.f, 0.f, 0.f, 0.f, 0.f, 0.f};
#pragma unroll
  for (int rt = 0; rt < 2; ++rt) {
#pragma unroll
    for (int rg = 0; rg < 4; ++rg) {
      int row = mbase + rt * 16 + quad * 4 + rg;
      if (row < NN) {
        if (batch[row] == g0) {
#pragma unroll
          for (int ct = 0; ct < 8; ++ct)
            ps0[ct] += fmaxf(acc[rt][ct][rg] + bias[ct], 0.f);
        } else {
#pragma unroll
          for (int ct = 0; ct < 8; ++ct)
            ps1[ct] += fmaxf(acc[rt][ct][rg] + bias[ct], 0.f);
        }
      }
    }
  }

  // Fold the 4 quads (lanes lr, lr+16, lr+32, lr+48 share column ct*16+lr).
#pragma unroll
  for (int ct = 0; ct < 8; ++ct) {
    float a = ps0[ct];
    a += __shfl_xor(a, 16);
    a += __shfl_xor(a, 32);
    float b = ps1[ct];
    b += __shfl_xor(b, 16);
    b += __shfl_xor(b, 32);
    if (quad == 0) {  // 16 lanes x 8 ct -> full 128-column wave partials
      pool[wv][0][ct * 16 + lr] = a;
      pool[wv][1][ct * 16 + lr] = b;
    }
  }
  __syncthreads();

  if (tid < H) {
    float v = 0.f, w = 0.f;
#pragma unroll
    for (int s = 0; s < 8; ++s) {
      v += pool[s][0][tid];
      w += pool[s][1][tid];
    }
    atomicAdd(&gsum[g0 * H + tid], v);
    int rlast = bbase + 255; if (rlast > NN - 1) rlast = NN - 1;
    int g1 = batch[rlast];
    if (g1 != g0) atomicAdd(&gsum[g1 * H + tid], w);
  }
}

// ---------------- head ----------------
__global__ void k_head2(const float* __restrict__ gsum, const int* __restrict__ batch,
                        const float* __restrict__ W5, const float* __restrict__ b5,
                        const float* __restrict__ W6, const float* __restrict__ b6,
                        const float* __restrict__ W7, const float* __restrict__ b7,
                        const float* __restrict__ W8, const float* __restrict__ b8,
                        const float* __restrict__ Wl, const float* __restrict__ bl,
                        float* __restrict__ out) {
  __shared__ float s0[128], s1[128];
  __shared__ int sb[2];
  const int g = blockIdx.x, j = threadIdx.x;
  if (j < 2) {  // binary search for bounds of graph g (batch sorted)
    int tgt = g + j, lo = 0, hi = NN;
    while (lo < hi) {
      int mid = (lo + hi) >> 1;
      if (batch[mid] < tgt) lo = mid + 1; else hi = mid;
    }
    sb[j] = lo;
  }
  __syncthreads();
  float cnt = (float)(sb[1] - sb[0]);
  s0[j] = gsum[g * 128 + j] / fmaxf(cnt, 1.f);
  __syncthreads();
  const float* Ws[4] = {W5, W6, W7, W8};
  const float* bs[4] = {b5, b6, b7, b8};
  float* cur = s0;
  float* nxt = s1;
  for (int L = 0; L < 4; ++L) {
    const float* W = Ws[L];
    float a = bs[L][j];
    for (int k = 0; k < 128; ++k) a = fmaf(cur[k], W[k * 128 + j], a);
    nxt[j] = fmaxf(a, 0.f);
    __syncthreads();
    float* t = cur; cur = nxt; nxt = t;
  }
  if (j < 2) {
    float a = bl[j];
    for (int k = 0; k < 128; ++k) a = fmaf(cur[k], Wl[k * 2 + j], a);
    out[g * 2 + j] = 1.f / (1.f + __expf(-a));
  }
}

// ---------------- launch ----------------
static inline char* ws_take(char*& p, size_t bytes) {
  char* r = p;
  p += (bytes + 255) & ~(size_t)255;
  return r;
}

extern "C" void kernel_launch(void* const* d_in, const int* in_sizes, int n_in,
                              void* d_out, int out_size, void* d_ws, size_t ws_size,
                              hipStream_t stream) {
  const float* x0 = (const float*)d_in[0];
  const int* ei = (const int*)d_in[1];
  const int* batch = (const int*)d_in[2];
  const float* Wr[4] = {(const float*)d_in[3], (const float*)d_in[6],
                        (const float*)d_in[9], (const float*)d_in[12]};
  const float* brr[4] = {(const float*)d_in[4], (const float*)d_in[7],
                         (const float*)d_in[10], (const float*)d_in[13]};
  const float* Wo[4] = {(const float*)d_in[5], (const float*)d_in[8],
                        (const float*)d_in[11], (const float*)d_in[14]};
  const float* W5 = (const float*)d_in[15];
  const float* b5 = (const float*)d_in[16];
  const float* W6 = (const float*)d_in[17];
  const float* b6 = (const float*)d_in[18];
  const float* W7 = (const float*)d_in[19];
  const float* b7 = (const float*)d_in[20];
  const float* W8 = (const float*)d_in[21];
  const float* b8 = (const float*)d_in[22];
  const float* Wl = (const float*)d_in[23];
  const float* bl = (const float*)d_in[24];
  float* out = (float*)d_out;

  char* p = (char*)d_ws;
  int* fcnt = (int*)ws_take(p, (size_t)NN * 4);
  int* colp = (int*)ws_take(p, (size_t)NN * DMAX * 4);
  __hip_bfloat16* agg = (__hip_bfloat16*)ws_take(p, (size_t)NN * H * 2);
  unsigned char* f8a = (unsigned char*)ws_take(p, (size_t)(NN + 1) * H);  // fp8 ping
  unsigned char* f8b = (unsigned char*)ws_take(p, (size_t)(NN + 1) * H);  // fp8 pong
  float* gsum = (float*)ws_take(p, (size_t)NG * H * 4);
  __hip_bfloat16* wfall = (__hip_bfloat16*)ws_take(p, 3 * 32768 * 2);
  int* gbase = (int*)ws_take(p, NB * 4);
  __hip_bfloat16* wf1 = wfall;
  __hip_bfloat16* wf2 = wfall + 32768;
  __hip_bfloat16* wf3 = wfall + 65536;
  // pairs buffer (8 MB, R26 4B-packed) aliases agg (25.6 MB): CSR build
  // finishes before the first aggregation write to agg.
  unsigned* pairs = (unsigned*)agg;
  (void)ws_size; (void)in_sizes; (void)n_in; (void)out_size;

  k_init_wcvt<<<384 + (NB + NG * H + 64 + 255) / 256, 256, 0, stream>>>(
      gbase, gsum, (unsigned*)(f8a + (size_t)NN * H), (unsigned*)(f8b + (size_t)NN * H),
      Wr[1], Wo[1], Wr[2], Wo[2], Wr[3], Wo[3], wfall);
  k_bucket<<<512, 256, 0, stream>>>(ei, gbase, pairs);
  k_fill2<<<NB, 256, 0, stream>>>(pairs, gbase, fcnt, colp);

  // layer 1 (F_IN=4): fused gather + GEMM -> fp8 (R25c); also writes sentinels
  k_l1<<<NN / 16, 256, 0, stream>>>(x0, fcnt, colp, Wr[0], Wo[0], brr[0], f8a);

  // layers 2-4: fp8 gather-agg + MFMA GEMM (512-thread, R27), fp8-only
  // activations ping-pong (R17-R19, R22). Layer 4 fuses the mean pool.
  k_aggf8<<<6250, 256, 0, stream>>>((const uint2*)f8a, fcnt, colp, (uintx4*)agg);
  k_gemm_mfma<<<391, 512, 0, stream>>>(agg, f8a, wf1, brr[1], f8b);
  k_aggf8<<<6250, 256, 0, stream>>>((const uint2*)f8b, fcnt, colp, (uintx4*)agg);
  k_gemm_mfma<<<391, 512, 0, stream>>>(agg, f8b, wf2, brr[2], f8a);
  k_aggf8<<<6250, 256, 0, stream>>>((const uint2*)f8a, fcnt, colp, (uintx4*)agg);
  k_gemm_mfma_pool<<<391, 512, 0, stream>>>(agg, f8a, wf3, brr[3], batch, gsum);

  // MLP head + sigmoid
  k_head2<<<NG, 128, 0, stream>>>(gsum, batch, W5, b5, W6, b6, W7, b7, W8, b8, Wl, bl, out);
}